// Round 1
// baseline (1822.085 us; speedup 1.0000x reference)
//
#include <hip/hip_runtime.h>
#include <math.h>

// TransformerBlock fp32 baseline for MI355X.
// x:[4,2048,512] -> out:[4,2048,512]
// Pipeline: LN1 -> qkv GEMM -> flash attention -> out-proj GEMM (+bias+res)
//           -> LN2 -> ff1 GEMM (+bias+GELU) -> ff2 GEMM (+bias+res)
// ws layout (floats): bufA[8192*512] | bufB[8192*1536] | bufC[8192*512]  = 84 MB

#define TOKENS 8192
#define SEQ    2048

// ---------------------------------------------------------------------------
// LayerNorm: one wave per 512-float row; block = 256 threads = 4 rows.
// ---------------------------------------------------------------------------
__global__ __launch_bounds__(256) void ln_k(const float* __restrict__ x,
                                            const float* __restrict__ g,
                                            const float* __restrict__ bta,
                                            float* __restrict__ o) {
    const int lane = threadIdx.x & 63;
    const int row  = (blockIdx.x << 2) + (threadIdx.x >> 6);
    const float* xr = x + ((size_t)row << 9) + (lane << 3);
    float4 a = *(const float4*)xr;
    float4 c = *(const float4*)(xr + 4);
    float s  = a.x + a.y + a.z + a.w + c.x + c.y + c.z + c.w;
    float ss = a.x*a.x + a.y*a.y + a.z*a.z + a.w*a.w
             + c.x*c.x + c.y*c.y + c.z*c.z + c.w*c.w;
#pragma unroll
    for (int m = 32; m; m >>= 1) {
        s  += __shfl_xor(s, m, 64);
        ss += __shfl_xor(ss, m, 64);
    }
    const float mu   = s * (1.0f / 512.0f);
    const float rstd = rsqrtf(ss * (1.0f / 512.0f) - mu * mu + 1e-5f);
    const float4 g0 = *(const float4*)(g + (lane << 3));
    const float4 g1 = *(const float4*)(g + (lane << 3) + 4);
    const float4 b0 = *(const float4*)(bta + (lane << 3));
    const float4 b1 = *(const float4*)(bta + (lane << 3) + 4);
    float4 r0, r1;
    r0.x = (a.x - mu) * rstd * g0.x + b0.x;
    r0.y = (a.y - mu) * rstd * g0.y + b0.y;
    r0.z = (a.z - mu) * rstd * g0.z + b0.z;
    r0.w = (a.w - mu) * rstd * g0.w + b0.w;
    r1.x = (c.x - mu) * rstd * g1.x + b1.x;
    r1.y = (c.y - mu) * rstd * g1.y + b1.y;
    r1.z = (c.z - mu) * rstd * g1.z + b1.z;
    r1.w = (c.w - mu) * rstd * g1.w + b1.w;
    float* orow = o + ((size_t)row << 9) + (lane << 3);
    *(float4*)orow       = r0;
    *(float4*)(orow + 4) = r1;
}

// ---------------------------------------------------------------------------
// fp32 GEMM: C[M,N] = A[M,K] @ B[K,N], 128x128 tile, BK=8, 8x8 acc/thread.
// EPI: 0 = none, 1 = +bias, 2 = +bias then exact GELU, 3 = +bias +residual
// ---------------------------------------------------------------------------
__device__ __forceinline__ float gelu_exact(float v) {
    return 0.5f * v * (1.0f + erff(v * 0.70710678118654752f));
}

template <int EPI>
__global__ __launch_bounds__(256) void gemm_k(const float* __restrict__ A,
                                              const float* __restrict__ B,
                                              const float* __restrict__ bias,
                                              const float* __restrict__ res,
                                              float* __restrict__ C,
                                              int M, int N, int K) {
    __shared__ float As[8][132];  // [k][m], pad 132 (528B rows, 16B aligned)
    __shared__ float Bs[8][132];  // [k][n]
    const int tid = threadIdx.x;
    const int bm = blockIdx.y << 7, bn = blockIdx.x << 7;
    const int tx = tid & 15, ty = tid >> 4;
    const int ar = tid >> 1, ak = (tid & 1) << 2;      // A tile: 128r x 8k
    const int bk = tid >> 5, bn4 = (tid & 31) << 2;    // B tile: 8k x 128n
    const float* Ap = A + (size_t)(bm + ar) * K + ak;
    const float* Bp = B + (size_t)bk * N + bn + bn4;
    const size_t bstep = (size_t)8 * N;
    float acc[8][8] = {};
    for (int k0 = 0; k0 < K; k0 += 8) {
        float4 av = *(const float4*)Ap; Ap += 8;
        float4 bv = *(const float4*)Bp; Bp += bstep;
        __syncthreads();
        As[ak + 0][ar] = av.x;
        As[ak + 1][ar] = av.y;
        As[ak + 2][ar] = av.z;
        As[ak + 3][ar] = av.w;
        *(float4*)&Bs[bk][bn4] = bv;
        __syncthreads();
#pragma unroll
        for (int kk = 0; kk < 8; kk++) {
            float4 a0 = *(const float4*)&As[kk][ty << 3];
            float4 a1 = *(const float4*)&As[kk][(ty << 3) + 4];
            float4 b0 = *(const float4*)&Bs[kk][tx << 3];
            float4 b1 = *(const float4*)&Bs[kk][(tx << 3) + 4];
            float av8[8] = {a0.x, a0.y, a0.z, a0.w, a1.x, a1.y, a1.z, a1.w};
            float bv8[8] = {b0.x, b0.y, b0.z, b0.w, b1.x, b1.y, b1.z, b1.w};
#pragma unroll
            for (int i = 0; i < 8; i++)
#pragma unroll
                for (int j = 0; j < 8; j++) acc[i][j] += av8[i] * bv8[j];
        }
    }
    // epilogue
    const int row0 = bm + (ty << 3);
    const int col  = bn + (tx << 3);
    float4 bs0, bs1;
    if constexpr (EPI >= 1) {
        bs0 = *(const float4*)(bias + col);
        bs1 = *(const float4*)(bias + col + 4);
    }
#pragma unroll
    for (int i = 0; i < 8; i++) {
        const size_t off = (size_t)(row0 + i) * N + col;
        float v[8];
#pragma unroll
        for (int j = 0; j < 8; j++) v[j] = acc[i][j];
        if constexpr (EPI >= 1) {
            v[0] += bs0.x; v[1] += bs0.y; v[2] += bs0.z; v[3] += bs0.w;
            v[4] += bs1.x; v[5] += bs1.y; v[6] += bs1.z; v[7] += bs1.w;
        }
        if constexpr (EPI == 2) {
#pragma unroll
            for (int j = 0; j < 8; j++) v[j] = gelu_exact(v[j]);
        }
        if constexpr (EPI == 3) {
            float4 rr0 = *(const float4*)(res + off);
            float4 rr1 = *(const float4*)(res + off + 4);
            v[0] += rr0.x; v[1] += rr0.y; v[2] += rr0.z; v[3] += rr0.w;
            v[4] += rr1.x; v[5] += rr1.y; v[6] += rr1.z; v[7] += rr1.w;
        }
        float4 o0 = {v[0], v[1], v[2], v[3]};
        float4 o1 = {v[4], v[5], v[6], v[7]};
        *(float4*)(C + off)     = o0;
        *(float4*)(C + off + 4) = o1;
    }
}

// ---------------------------------------------------------------------------
// Flash attention: grid (32 q-tiles, 32 b*h). Block 256 thr, 64-row Q tile,
// 64-key K/V tiles, online softmax. P tile reuses Ks LDS. Scores scaled by
// 1/8 folded into Q at load. qkv:[8192][1536] (q|k|v, head h at col h*64).
// out: attended in [b,n,h*64+d] layout = [8192][512].
// ---------------------------------------------------------------------------
__global__ __launch_bounds__(256) void attn_k(const float* __restrict__ qkv,
                                              float* __restrict__ out) {
    __shared__ float Qs[64][68];
    __shared__ float Ks[64][68];  // K^T-ish (swizzled); reused to hold P
    __shared__ float Vs[64][68];
    const int tid = threadIdx.x;
    const int qt = blockIdx.x, bh = blockIdx.y;
    const int b = bh >> 3, h = bh & 7;
    const size_t tokbase = (size_t)b * SEQ;
    const int q0 = qt << 6;
    const int tx = tid & 15, ty = tid >> 4;
    const int r0 = ty << 2, c0 = tx << 2;  // 4x4 S-block / 4x4 O-block per thr

    {   // load Q tile, scale by 1/sqrt(64)=0.125
        const int lr = tid >> 4;
        const int c4 = (tid & 15) << 2;
#pragma unroll
        for (int i = 0; i < 4; i++) {
            const int r = (i << 4) + lr;
            const float* p = qkv + (tokbase + q0 + r) * 1536 + h * 64 + c4;
            float4 v = *(const float4*)p;
            v.x *= 0.125f; v.y *= 0.125f; v.z *= 0.125f; v.w *= 0.125f;
            *(float4*)&Qs[r][c4] = v;
        }
    }

    float m[4], l[4], o[4][4];
#pragma unroll
    for (int i = 0; i < 4; i++) {
        m[i] = -1e30f; l[i] = 0.0f;
#pragma unroll
        for (int j = 0; j < 4; j++) o[i][j] = 0.0f;
    }

    for (int jt = 0; jt < 32; jt++) {
        __syncthreads();  // prev iter's P/V reads done
        {   // load K (xor-swizzled cols to kill bank conflicts) and V
            const int c  = (tid >> 4);
            const int d4 = (tid & 15) << 2;
#pragma unroll
            for (int i = 0; i < 4; i++) {
                const int cc = (i << 4) + c;
                const float* kp = qkv + (tokbase + (jt << 6) + cc) * 1536 + 512 + h * 64 + d4;
                float4 kv = *(const float4*)kp;
                const int sw = ((cc >> 2) & 7) << 2;
                *(float4*)&Ks[cc][d4 ^ sw] = kv;
                float4 vv = *(const float4*)(kp + 512);
                *(float4*)&Vs[cc][d4] = vv;
            }
        }
        __syncthreads();

        // S[r0..+3][c0..+3] = Q Kt
        float s[4][4] = {};
#pragma unroll
        for (int kk = 0; kk < 64; kk += 4) {
            float4 qv[4], kv[4];
#pragma unroll
            for (int i = 0; i < 4; i++) qv[i] = *(const float4*)&Qs[r0 + i][kk];
#pragma unroll
            for (int j = 0; j < 4; j++) {
                const int cc = c0 + j;
                kv[j] = *(const float4*)&Ks[cc][kk ^ (((cc >> 2) & 7) << 2)];
            }
#pragma unroll
            for (int i = 0; i < 4; i++)
#pragma unroll
                for (int j = 0; j < 4; j++)
                    s[i][j] += qv[i].x * kv[j].x + qv[i].y * kv[j].y +
                               qv[i].z * kv[j].z + qv[i].w * kv[j].w;
        }

        // online softmax (row reduce across the 16 tx-lanes of this row group)
#pragma unroll
        for (int i = 0; i < 4; i++) {
            float rm = fmaxf(fmaxf(s[i][0], s[i][1]), fmaxf(s[i][2], s[i][3]));
            rm = fmaxf(rm, __shfl_xor(rm, 1, 64));
            rm = fmaxf(rm, __shfl_xor(rm, 2, 64));
            rm = fmaxf(rm, __shfl_xor(rm, 4, 64));
            rm = fmaxf(rm, __shfl_xor(rm, 8, 64));
            const float mn = fmaxf(m[i], rm);
            const float alpha = __expf(m[i] - mn);
            float rs = 0.0f;
#pragma unroll
            for (int j = 0; j < 4; j++) { s[i][j] = __expf(s[i][j] - mn); rs += s[i][j]; }
            rs += __shfl_xor(rs, 1, 64);
            rs += __shfl_xor(rs, 2, 64);
            rs += __shfl_xor(rs, 4, 64);
            rs += __shfl_xor(rs, 8, 64);
            l[i] = l[i] * alpha + rs;
            m[i] = mn;
#pragma unroll
            for (int j = 0; j < 4; j++) o[i][j] *= alpha;
        }

        __syncthreads();  // all Ks reads done -> safe to overwrite with P
#pragma unroll
        for (int i = 0; i < 4; i++) {
            float4 pv = {s[i][0], s[i][1], s[i][2], s[i][3]};
            *(float4*)&Ks[r0 + i][c0] = pv;  // P[r][c], unswizzled
        }
        __syncthreads();

        // O += P @ V   (o[i][k], d0 = c0)
#pragma unroll
        for (int c = 0; c < 64; c += 4) {
            float4 pv[4], vv[4];
#pragma unroll
            for (int i = 0; i < 4; i++) pv[i] = *(const float4*)&Ks[r0 + i][c];
#pragma unroll
            for (int j = 0; j < 4; j++) vv[j] = *(const float4*)&Vs[c + j][c0];
#pragma unroll
            for (int i = 0; i < 4; i++) {
                o[i][0] += pv[i].x * vv[0].x + pv[i].y * vv[1].x + pv[i].z * vv[2].x + pv[i].w * vv[3].x;
                o[i][1] += pv[i].x * vv[0].y + pv[i].y * vv[1].y + pv[i].z * vv[2].y + pv[i].w * vv[3].y;
                o[i][2] += pv[i].x * vv[0].z + pv[i].y * vv[1].z + pv[i].z * vv[2].z + pv[i].w * vv[3].z;
                o[i][3] += pv[i].x * vv[0].w + pv[i].y * vv[1].w + pv[i].z * vv[2].w + pv[i].w * vv[3].w;
            }
        }
    }

#pragma unroll
    for (int i = 0; i < 4; i++) {
        const float inv = 1.0f / l[i];
        float4 r = {o[i][0] * inv, o[i][1] * inv, o[i][2] * inv, o[i][3] * inv};
        *(float4*)(out + (tokbase + q0 + r0 + i) * 512 + h * 64 + c0) = r;
    }
}

// ---------------------------------------------------------------------------
extern "C" void kernel_launch(void* const* d_in, const int* in_sizes, int n_in,
                              void* d_out, int out_size, void* d_ws, size_t ws_size,
                              hipStream_t stream) {
    const float* x     = (const float*)d_in[0];
    const float* ln1_g = (const float*)d_in[1];
    const float* ln1_b = (const float*)d_in[2];
    const float* w_qkv = (const float*)d_in[3];
    const float* w_out = (const float*)d_in[4];
    const float* b_out = (const float*)d_in[5];
    const float* ln2_g = (const float*)d_in[6];
    const float* ln2_b = (const float*)d_in[7];
    const float* w1    = (const float*)d_in[8];
    const float* b1    = (const float*)d_in[9];
    const float* w2    = (const float*)d_in[10];
    const float* b2    = (const float*)d_in[11];
    float* out  = (float*)d_out;
    float* bufA = (float*)d_ws;                       // 8192*512  (h / attended / h2)
    float* bufB = bufA + (size_t)TOKENS * 512;        // 8192*1536 (qkv / ff)
    float* bufC = bufB + (size_t)TOKENS * 1536;       // 8192*512  (x2)

    ln_k<<<TOKENS / 4, 256, 0, stream>>>(x, ln1_g, ln1_b, bufA);
    gemm_k<0><<<dim3(12, 64), 256, 0, stream>>>(bufA, w_qkv, nullptr, nullptr, bufB,
                                                TOKENS, 1536, 512);
    attn_k<<<dim3(32, 32), 256, 0, stream>>>(bufB, bufA);
    gemm_k<3><<<dim3(4, 64), 256, 0, stream>>>(bufA, w_out, b_out, x, bufC,
                                               TOKENS, 512, 512);
    ln_k<<<TOKENS / 4, 256, 0, stream>>>(bufC, ln2_g, ln2_b, bufA);
    gemm_k<2><<<dim3(8, 64), 256, 0, stream>>>(bufA, w1, b1, nullptr, bufB,
                                               TOKENS, 1024, 512);
    gemm_k<3><<<dim3(4, 64), 256, 0, stream>>>(bufB, w2, b2, bufC, out,
                                               TOKENS, 512, 1024);
}

// Round 2
// 870.108 us; speedup vs baseline: 2.0941x; 2.0941x over previous
//
#include <hip/hip_runtime.h>
#include <math.h>

// TransformerBlock for MI355X.
// Round 2: attention via split-bf16 (hi+lo) MFMA, fp32-grade accuracy.
// ws layout (floats): bufA[8192*512] | bufB[8192*1536] | bufC[8192*512]
// During attention, bufC hosts vt_hi/vt_lo (transposed V, bf16) = exactly 16.78MB.

#define TOKENS 8192
#define SEQ    2048

typedef __attribute__((ext_vector_type(8))) short bf16x8;
typedef __attribute__((ext_vector_type(4))) float f32x4;
typedef __attribute__((ext_vector_type(4))) unsigned short u16x4;

__device__ __forceinline__ unsigned short f2bf(float f) {
    unsigned u = __builtin_bit_cast(unsigned, f);
    u += 0x7fffu + ((u >> 16) & 1u);
    return (unsigned short)(u >> 16);
}
__device__ __forceinline__ float bf2f(unsigned short h) {
    unsigned u = ((unsigned)h) << 16;
    return __builtin_bit_cast(float, u);
}

// ---------------------------------------------------------------------------
// LayerNorm: one wave per 512-float row; block = 256 threads = 4 rows.
// ---------------------------------------------------------------------------
__global__ __launch_bounds__(256) void ln_k(const float* __restrict__ x,
                                            const float* __restrict__ g,
                                            const float* __restrict__ bta,
                                            float* __restrict__ o) {
    const int lane = threadIdx.x & 63;
    const int row  = (blockIdx.x << 2) + (threadIdx.x >> 6);
    const float* xr = x + ((size_t)row << 9) + (lane << 3);
    float4 a = *(const float4*)xr;
    float4 c = *(const float4*)(xr + 4);
    float s  = a.x + a.y + a.z + a.w + c.x + c.y + c.z + c.w;
    float ss = a.x*a.x + a.y*a.y + a.z*a.z + a.w*a.w
             + c.x*c.x + c.y*c.y + c.z*c.z + c.w*c.w;
#pragma unroll
    for (int m = 32; m; m >>= 1) {
        s  += __shfl_xor(s, m, 64);
        ss += __shfl_xor(ss, m, 64);
    }
    const float mu   = s * (1.0f / 512.0f);
    const float rstd = rsqrtf(ss * (1.0f / 512.0f) - mu * mu + 1e-5f);
    const float4 g0 = *(const float4*)(g + (lane << 3));
    const float4 g1 = *(const float4*)(g + (lane << 3) + 4);
    const float4 b0 = *(const float4*)(bta + (lane << 3));
    const float4 b1 = *(const float4*)(bta + (lane << 3) + 4);
    float4 r0, r1;
    r0.x = (a.x - mu) * rstd * g0.x + b0.x;
    r0.y = (a.y - mu) * rstd * g0.y + b0.y;
    r0.z = (a.z - mu) * rstd * g0.z + b0.z;
    r0.w = (a.w - mu) * rstd * g0.w + b0.w;
    r1.x = (c.x - mu) * rstd * g1.x + b1.x;
    r1.y = (c.y - mu) * rstd * g1.y + b1.y;
    r1.z = (c.z - mu) * rstd * g1.z + b1.z;
    r1.w = (c.w - mu) * rstd * g1.w + b1.w;
    float* orow = o + ((size_t)row << 9) + (lane << 3);
    *(float4*)orow       = r0;
    *(float4*)(orow + 4) = r1;
}

// ---------------------------------------------------------------------------
// fp32 GEMM: C[M,N] = A[M,K] @ B[K,N], 128x128 tile, BK=8, 8x8 acc/thread.
// EPI: 0 = none, 1 = +bias, 2 = +bias then exact GELU, 3 = +bias +residual
// ---------------------------------------------------------------------------
__device__ __forceinline__ float gelu_exact(float v) {
    return 0.5f * v * (1.0f + erff(v * 0.70710678118654752f));
}

template <int EPI>
__global__ __launch_bounds__(256) void gemm_k(const float* __restrict__ A,
                                              const float* __restrict__ B,
                                              const float* __restrict__ bias,
                                              const float* __restrict__ res,
                                              float* __restrict__ C,
                                              int M, int N, int K) {
    __shared__ float As[8][132];
    __shared__ float Bs[8][132];
    const int tid = threadIdx.x;
    const int bm = blockIdx.y << 7, bn = blockIdx.x << 7;
    const int tx = tid & 15, ty = tid >> 4;
    const int ar = tid >> 1, ak = (tid & 1) << 2;
    const int bk = tid >> 5, bn4 = (tid & 31) << 2;
    const float* Ap = A + (size_t)(bm + ar) * K + ak;
    const float* Bp = B + (size_t)bk * N + bn + bn4;
    const size_t bstep = (size_t)8 * N;
    float acc[8][8] = {};
    for (int k0 = 0; k0 < K; k0 += 8) {
        float4 av = *(const float4*)Ap; Ap += 8;
        float4 bv = *(const float4*)Bp; Bp += bstep;
        __syncthreads();
        As[ak + 0][ar] = av.x;
        As[ak + 1][ar] = av.y;
        As[ak + 2][ar] = av.z;
        As[ak + 3][ar] = av.w;
        *(float4*)&Bs[bk][bn4] = bv;
        __syncthreads();
#pragma unroll
        for (int kk = 0; kk < 8; kk++) {
            float4 a0 = *(const float4*)&As[kk][ty << 3];
            float4 a1 = *(const float4*)&As[kk][(ty << 3) + 4];
            float4 b0 = *(const float4*)&Bs[kk][tx << 3];
            float4 b1 = *(const float4*)&Bs[kk][(tx << 3) + 4];
            float av8[8] = {a0.x, a0.y, a0.z, a0.w, a1.x, a1.y, a1.z, a1.w};
            float bv8[8] = {b0.x, b0.y, b0.z, b0.w, b1.x, b1.y, b1.z, b1.w};
#pragma unroll
            for (int i = 0; i < 8; i++)
#pragma unroll
                for (int j = 0; j < 8; j++) acc[i][j] += av8[i] * bv8[j];
        }
    }
    const int row0 = bm + (ty << 3);
    const int col  = bn + (tx << 3);
    float4 bs0, bs1;
    if constexpr (EPI >= 1) {
        bs0 = *(const float4*)(bias + col);
        bs1 = *(const float4*)(bias + col + 4);
    }
#pragma unroll
    for (int i = 0; i < 8; i++) {
        const size_t off = (size_t)(row0 + i) * N + col;
        float v[8];
#pragma unroll
        for (int j = 0; j < 8; j++) v[j] = acc[i][j];
        if constexpr (EPI >= 1) {
            v[0] += bs0.x; v[1] += bs0.y; v[2] += bs0.z; v[3] += bs0.w;
            v[4] += bs1.x; v[5] += bs1.y; v[6] += bs1.z; v[7] += bs1.w;
        }
        if constexpr (EPI == 2) {
#pragma unroll
            for (int j = 0; j < 8; j++) v[j] = gelu_exact(v[j]);
        }
        if constexpr (EPI == 3) {
            float4 rr0 = *(const float4*)(res + off);
            float4 rr1 = *(const float4*)(res + off + 4);
            v[0] += rr0.x; v[1] += rr0.y; v[2] += rr0.z; v[3] += rr0.w;
            v[4] += rr1.x; v[5] += rr1.y; v[6] += rr1.z; v[7] += rr1.w;
        }
        float4 o0 = {v[0], v[1], v[2], v[3]};
        float4 o1 = {v[4], v[5], v[6], v[7]};
        *(float4*)(C + off)     = o0;
        *(float4*)(C + off + 4) = o1;
    }
}

// ---------------------------------------------------------------------------
// V convert+transpose: qkv fp32 V part -> vt_hi/vt_lo bf16, layout
// [bh][64 d][2048 key]. Grid (32 key-tiles, 32 bh), 256 threads.
// ---------------------------------------------------------------------------
__global__ __launch_bounds__(256) void vconv_k(const float* __restrict__ qkv,
                                               unsigned short* __restrict__ vth,
                                               unsigned short* __restrict__ vtl) {
    __shared__ float vt[64][68];
    const int tid = threadIdx.x;
    const int kt = blockIdx.x, bh = blockIdx.y;
    const int b = bh >> 3, h = bh & 7;
    {
        const int key = tid >> 2, d16 = (tid & 3) << 4;
        const float* p = qkv + (size_t)(b * SEQ + (kt << 6) + key) * 1536 + 1024 + (h << 6) + d16;
#pragma unroll
        for (int i = 0; i < 4; i++)
            *(float4*)&vt[key][d16 + (i << 2)] = *(const float4*)(p + (i << 2));
    }
    __syncthreads();
    {
        const int d = tid >> 2, kc = (tid & 3) << 4;
        union { unsigned short us[16]; uint4 q[2]; } H, L;
#pragma unroll
        for (int i = 0; i < 16; i++) {
            float f = vt[kc + i][d];
            unsigned short hh = f2bf(f);
            H.us[i] = hh;
            L.us[i] = f2bf(f - bf2f(hh));
        }
        const size_t base = ((size_t)bh << 17) + ((size_t)d << 11) + (kt << 6) + kc;
        *(uint4*)&vth[base]     = H.q[0];
        *(uint4*)&vth[base + 8] = H.q[1];
        *(uint4*)&vtl[base]     = L.q[0];
        *(uint4*)&vtl[base + 8] = L.q[1];
    }
}

// ---------------------------------------------------------------------------
// Flash attention, split-bf16 MFMA (3 terms: hi*hi + hi*lo + lo*hi).
// Grid (32 q-tiles of 64 rows, 32 bh), block 256 = 4 waves; wave owns 16 q rows.
// St = K·Qᵀ via mfma_f32_16x16x32_bf16 (C: col=lane&15=q, row=quad*4+reg=key).
// P round-trips LDS (C-layout -> A-layout A[m=lane&15][k=quad*8+j]).
// K staged in LDS hi/lo with XOR 16B-chunk swizzle; V read from vt (bf16 global).
// LDS = Kh|Kl|Ph|Pl = 4*8KB = 32KB.
// ---------------------------------------------------------------------------
__global__ __launch_bounds__(256, 4) void attn_k(const float* __restrict__ qkv,
                                                 const unsigned short* __restrict__ vth,
                                                 const unsigned short* __restrict__ vtl,
                                                 float* __restrict__ out) {
    __shared__ unsigned short sm[16384];  // Kh[0] Kl[4096] Ph[8192] Pl[12288]
    const int tid  = threadIdx.x;
    const int lane = tid & 63;
    const int wv   = tid >> 6;
    const int col  = lane & 15;
    const int quad = lane >> 4;
    const int qt = blockIdx.x, bh = blockIdx.y;
    const int b = bh >> 3, h = bh & 7;
    const size_t tok0 = (size_t)b * SEQ;
    const int q0 = qt << 6;

    // Q fragments in registers for the whole kernel (0.125 scale folded in).
    bf16x8 qfh[2], qfl[2];
    {
        const int qrow = q0 + (wv << 4) + col;
        const float* qp = qkv + (tok0 + qrow) * 1536 + (h << 6) + (quad << 3);
#pragma unroll
        for (int kc = 0; kc < 2; kc++) {
            float v[8];
            *(float4*)&v[0] = *(const float4*)(qp + (kc << 5));
            *(float4*)&v[4] = *(const float4*)(qp + (kc << 5) + 4);
            union { unsigned short us[8]; bf16x8 v8; } H, L;
#pragma unroll
            for (int i = 0; i < 8; i++) {
                float f = v[i] * 0.125f;
                unsigned short hh = f2bf(f);
                H.us[i] = hh;
                L.us[i] = f2bf(f - bf2f(hh));
            }
            qfh[kc] = H.v8; qfl[kc] = L.v8;
        }
    }

    const f32x4 zero4 = {0.0f, 0.0f, 0.0f, 0.0f};
    f32x4 o[4] = {zero4, zero4, zero4, zero4};
    float m_run = -1e30f, l_run = 0.0f;

    const int skey = tid >> 2;        // staging key row 0..63
    const int sc   = (tid & 3) << 1;  // staging first 16B chunk (of 8 per row)
    const float* kgp = qkv + (tok0 + skey) * 1536 + 512 + (h << 6) + (sc << 3);
    const size_t vbase = ((size_t)bh << 17) + (quad << 3);

    for (int jt = 0; jt < 32; jt++) {
        __syncthreads();  // previous tile's K-frag reads complete
        {   // stage K tile -> LDS hi/lo bf16, swizzled 16B chunks
            const float* kp = kgp + (size_t)(jt << 6) * 1536;
            float v[16];
#pragma unroll
            for (int i = 0; i < 4; i++)
                *(float4*)&v[i << 2] = *(const float4*)(kp + (i << 2));
            union { unsigned short us[8]; bf16x8 v8; } H0, H1, L0, L1;
#pragma unroll
            for (int i = 0; i < 8; i++) {
                unsigned short h0 = f2bf(v[i]);
                H0.us[i] = h0; L0.us[i] = f2bf(v[i] - bf2f(h0));
                unsigned short h1 = f2bf(v[8 + i]);
                H1.us[i] = h1; L1.us[i] = f2bf(v[8 + i] - bf2f(h1));
            }
            const int r64 = skey << 6, k7 = skey & 7;
            *(bf16x8*)&sm[r64 + ((sc ^ k7) << 3)]              = H0.v8;
            *(bf16x8*)&sm[r64 + (((sc + 1) ^ k7) << 3)]        = H1.v8;
            *(bf16x8*)&sm[4096 + r64 + ((sc ^ k7) << 3)]       = L0.v8;
            *(bf16x8*)&sm[4096 + r64 + (((sc + 1) ^ k7) << 3)] = L1.v8;
        }
        __syncthreads();

        // ---- St[key][q] = K · Qᵀ  (4 key-blocks × 2 k-chunks × 3 terms) ----
        f32x4 st[4] = {zero4, zero4, zero4, zero4};
#pragma unroll
        for (int kb = 0; kb < 4; kb++) {
            const int row = (kb << 4) + col;
            const int r64 = row << 6, r7 = row & 7;
#pragma unroll
            for (int kc = 0; kc < 2; kc++) {
                const int ch = (((kc << 2) + quad) ^ r7) << 3;
                bf16x8 kh = *(const bf16x8*)&sm[r64 + ch];
                bf16x8 kl = *(const bf16x8*)&sm[4096 + r64 + ch];
                st[kb] = __builtin_amdgcn_mfma_f32_16x16x32_bf16(kh, qfh[kc], st[kb], 0, 0, 0);
                st[kb] = __builtin_amdgcn_mfma_f32_16x16x32_bf16(kh, qfl[kc], st[kb], 0, 0, 0);
                st[kb] = __builtin_amdgcn_mfma_f32_16x16x32_bf16(kl, qfh[kc], st[kb], 0, 0, 0);
            }
        }

        // ---- online softmax (this lane's column q = col; 16 keys local) ----
        float mx = st[0][0];
#pragma unroll
        for (int kb = 0; kb < 4; kb++)
#pragma unroll
            for (int r = 0; r < 4; r++) mx = fmaxf(mx, st[kb][r]);
        mx = fmaxf(mx, __shfl_xor(mx, 16));
        mx = fmaxf(mx, __shfl_xor(mx, 32));
        const float mn = fmaxf(m_run, mx);
        const float al = __expf(m_run - mn);
        m_run = mn;
        float p[16];
        float rs = 0.0f;
#pragma unroll
        for (int kb = 0; kb < 4; kb++)
#pragma unroll
            for (int r = 0; r < 4; r++) {
                float e = __expf(st[kb][r] - mn);
                p[(kb << 2) + r] = e;
                rs += e;
            }
        rs += __shfl_xor(rs, 16);
        rs += __shfl_xor(rs, 32);
        l_run = l_run * al + rs;
        float aO[4];
#pragma unroll
        for (int r = 0; r < 4; r++) aO[r] = __shfl(al, (quad << 2) + r);
#pragma unroll
        for (int db = 0; db < 4; db++) {
            o[db][0] *= aO[0]; o[db][1] *= aO[1];
            o[db][2] *= aO[2]; o[db][3] *= aO[3];
        }

        // ---- P (hi/lo) -> LDS: C-layout regs to row-major P[q][key] ----
        const int prow = (wv << 4) + col;
        const int p64 = prow << 6, p7 = col & 7;
#pragma unroll
        for (int kb = 0; kb < 4; kb++) {
            u16x4 hv, lv;
#pragma unroll
            for (int r = 0; r < 4; r++) {
                float e = p[(kb << 2) + r];
                unsigned short hh = f2bf(e);
                hv[r] = hh;
                lv[r] = f2bf(e - bf2f(hh));
            }
            const int ch = ((kb << 1) + (quad >> 1)) ^ p7;
            const int off = p64 + (ch << 3) + ((quad & 1) << 2);
            *(u16x4*)&sm[8192  + off] = hv;
            *(u16x4*)&sm[12288 + off] = lv;
        }

        // ---- O += P · V  (A = P from LDS, B = Vt from global bf16) ----
        bf16x8 pfh[2], pfl[2];
#pragma unroll
        for (int kc = 0; kc < 2; kc++) {
            const int ch = (((kc << 2) + quad) ^ p7) << 3;
            pfh[kc] = *(const bf16x8*)&sm[8192  + p64 + ch];
            pfl[kc] = *(const bf16x8*)&sm[12288 + p64 + ch];
        }
        const size_t vjt = vbase + (jt << 6);
#pragma unroll
        for (int db = 0; db < 4; db++) {
            const size_t doff = vjt + ((size_t)((db << 4) + col) << 11);
#pragma unroll
            for (int kc = 0; kc < 2; kc++) {
                const size_t goff = doff + (kc << 5);
                bf16x8 vh = *(const bf16x8*)(vth + goff);
                bf16x8 vl = *(const bf16x8*)(vtl + goff);
                o[db] = __builtin_amdgcn_mfma_f32_16x16x32_bf16(pfh[kc], vh, o[db], 0, 0, 0);
                o[db] = __builtin_amdgcn_mfma_f32_16x16x32_bf16(pfh[kc], vl, o[db], 0, 0, 0);
                o[db] = __builtin_amdgcn_mfma_f32_16x16x32_bf16(pfl[kc], vh, o[db], 0, 0, 0);
            }
        }
    }

    // ---- epilogue: O / l, store fp32 [tok][h*64+d] ----
    float linv[4];
#pragma unroll
    for (int r = 0; r < 4; r++) linv[r] = 1.0f / __shfl(l_run, (quad << 2) + r);
    float* op = out + (tok0 + q0 + (wv << 4) + (quad << 2)) * 512 + (h << 6) + col;
#pragma unroll
    for (int r = 0; r < 4; r++)
#pragma unroll
        for (int db = 0; db < 4; db++)
            op[(size_t)r * 512 + (db << 4)] = o[db][r] * linv[r];
}

// ---------------------------------------------------------------------------
extern "C" void kernel_launch(void* const* d_in, const int* in_sizes, int n_in,
                              void* d_out, int out_size, void* d_ws, size_t ws_size,
                              hipStream_t stream) {
    const float* x     = (const float*)d_in[0];
    const float* ln1_g = (const float*)d_in[1];
    const float* ln1_b = (const float*)d_in[2];
    const float* w_qkv = (const float*)d_in[3];
    const float* w_out = (const float*)d_in[4];
    const float* b_out = (const float*)d_in[5];
    const float* ln2_g = (const float*)d_in[6];
    const float* ln2_b = (const float*)d_in[7];
    const float* w1    = (const float*)d_in[8];
    const float* b1    = (const float*)d_in[9];
    const float* w2    = (const float*)d_in[10];
    const float* b2    = (const float*)d_in[11];
    float* out  = (float*)d_out;
    float* bufA = (float*)d_ws;
    float* bufB = bufA + (size_t)TOKENS * 512;
    float* bufC = bufB + (size_t)TOKENS * 1536;
    unsigned short* vth = (unsigned short*)bufC;          // alive only during attention
    unsigned short* vtl = vth + ((size_t)32 << 17);       // 32 bh * 131072

    ln_k<<<TOKENS / 4, 256, 0, stream>>>(x, ln1_g, ln1_b, bufA);
    gemm_k<0><<<dim3(12, 64), 256, 0, stream>>>(bufA, w_qkv, nullptr, nullptr, bufB,
                                                TOKENS, 1536, 512);
    vconv_k<<<dim3(32, 32), 256, 0, stream>>>(bufB, vth, vtl);
    attn_k<<<dim3(32, 32), 256, 0, stream>>>(bufB, vth, vtl, bufA);
    gemm_k<3><<<dim3(4, 64), 256, 0, stream>>>(bufA, w_out, b_out, x, bufC,
                                               TOKENS, 512, 512);
    ln_k<<<TOKENS / 4, 256, 0, stream>>>(bufC, ln2_g, ln2_b, bufA);
    gemm_k<2><<<dim3(8, 64), 256, 0, stream>>>(bufA, w1, b1, nullptr, bufB,
                                               TOKENS, 1024, 512);
    gemm_k<3><<<dim3(4, 64), 256, 0, stream>>>(bufB, w2, b2, bufC, out,
                                               TOKENS, 512, 1024);
}

// Round 3
// 423.024 us; speedup vs baseline: 4.3073x; 2.0569x over previous
//
#include <hip/hip_runtime.h>
#include <math.h>

// TransformerBlock for MI355X — round 3: everything matmul-shaped on MFMA
// via 3-term split-bf16 (hi+lo); producers write pre-split operands.
// ws layout (75.5 MB):
//   W  [0, 8.39M)        : wqkvT h/l | woutT h/l | w1T h/l | w2T h/l  (bf16, [N][K])
//   R1 [8.39M, 25.2M)    : h hi/lo -> attended hi/lo -> h2 hi/lo   (8192*512 u16 x2)
//   R2 [25.2M, 41.9M)    : q fp32 -> x2 fp32                       (8192*512 f32)
//   R3 [41.9M, 75.5M)    : kh|kl|vth|vtl (bf16) -> gh|gl           (33.55M)

#define TOKENS 8192
#define SEQ    2048
typedef unsigned short u16;
typedef __attribute__((ext_vector_type(8))) short bf16x8;
typedef __attribute__((ext_vector_type(4))) float f32x4;
typedef __attribute__((ext_vector_type(4))) unsigned short u16x4;

__device__ __forceinline__ u16 f2bf(float f) {
    unsigned u = __builtin_bit_cast(unsigned, f);
    u += 0x7fffu + ((u >> 16) & 1u);
    return (u16)(u >> 16);
}
__device__ __forceinline__ float bf2f(u16 h) {
    unsigned u = ((unsigned)h) << 16;
    return __builtin_bit_cast(float, u);
}
__device__ __forceinline__ void a16(void* lds, const void* g) {
    __builtin_amdgcn_global_load_lds(
        (const __attribute__((address_space(1))) unsigned int*)g,
        (__attribute__((address_space(3))) unsigned int*)lds, 16, 0, 0);
}
__device__ __forceinline__ float gelu_exact(float v) {
    return 0.5f * v * (1.0f + erff(v * 0.70710678118654752f));
}

// ---------------------------------------------------------------------------
// LayerNorm -> split bf16 hi/lo. One wave per 512-f32 row, block = 4 rows.
// ---------------------------------------------------------------------------
__global__ __launch_bounds__(256) void ln_k(const float* __restrict__ x,
                                            const float* __restrict__ g,
                                            const float* __restrict__ bta,
                                            u16* __restrict__ oh,
                                            u16* __restrict__ ol) {
    const int lane = threadIdx.x & 63;
    const int row  = (blockIdx.x << 2) + (threadIdx.x >> 6);
    const float* xr = x + ((size_t)row << 9) + (lane << 3);
    float v[8];
    *(float4*)&v[0] = *(const float4*)xr;
    *(float4*)&v[4] = *(const float4*)(xr + 4);
    float s = 0.f, ss = 0.f;
#pragma unroll
    for (int i = 0; i < 8; i++) { s += v[i]; ss += v[i] * v[i]; }
#pragma unroll
    for (int m = 32; m; m >>= 1) {
        s  += __shfl_xor(s, m, 64);
        ss += __shfl_xor(ss, m, 64);
    }
    const float mu   = s * (1.0f / 512.0f);
    const float rstd = rsqrtf(ss * (1.0f / 512.0f) - mu * mu + 1e-5f);
    float gg[8], bb[8];
    *(float4*)&gg[0] = *(const float4*)(g + (lane << 3));
    *(float4*)&gg[4] = *(const float4*)(g + (lane << 3) + 4);
    *(float4*)&bb[0] = *(const float4*)(bta + (lane << 3));
    *(float4*)&bb[4] = *(const float4*)(bta + (lane << 3) + 4);
    union { u16 us[8]; uint4 q; } H, L;
#pragma unroll
    for (int i = 0; i < 8; i++) {
        float r = (v[i] - mu) * rstd * gg[i] + bb[i];
        u16 hi = f2bf(r);
        H.us[i] = hi;
        L.us[i] = f2bf(r - bf2f(hi));
    }
    const size_t o = ((size_t)row << 9) + (lane << 3);
    *(uint4*)&oh[o] = H.q;
    *(uint4*)&ol[o] = L.q;
}

// ---------------------------------------------------------------------------
// Weight transpose+split: src[K][N] f32 -> dh/dl[N][K] bf16. Grid (N/64,K/64).
// ---------------------------------------------------------------------------
__global__ __launch_bounds__(256) void wtconv_k(const float* __restrict__ src,
                                                u16* __restrict__ dh,
                                                u16* __restrict__ dl,
                                                int K, int N) {
    __shared__ float t[64][65];
    const int tid = threadIdx.x;
    const int n0 = blockIdx.x << 6, k0 = blockIdx.y << 6;
    {
        const int kr = tid >> 2, nc = (tid & 3) << 4;
        const float* p = src + (size_t)(k0 + kr) * N + n0 + nc;
#pragma unroll
        for (int i = 0; i < 4; i++)
            *(float4*)&t[kr][nc + (i << 2)] = *(const float4*)(p + (i << 2));
    }
    __syncthreads();
    {
        const int nr = tid >> 2, kc = (tid & 3) << 4;
        union { u16 us[16]; uint4 q[2]; } H, L;
#pragma unroll
        for (int i = 0; i < 16; i++) {
            float f = t[kc + i][nr];
            u16 hi = f2bf(f);
            H.us[i] = hi;
            L.us[i] = f2bf(f - bf2f(hi));
        }
        const size_t o = (size_t)(n0 + nr) * K + k0 + kc;
        *(uint4*)&dh[o] = H.q[0]; *(uint4*)&dh[o + 8] = H.q[1];
        *(uint4*)&dl[o] = L.q[0]; *(uint4*)&dl[o + 8] = L.q[1];
    }
}

// ---------------------------------------------------------------------------
// Split-bf16 MFMA GEMM: C[M,N] = A[M,K]B[K,N], A as Ah/Al [M][K] bf16,
// B as Bh/Bl [N][K] bf16 (pre-transposed). 128x128 tile, BK=32, 4 waves 2x2,
// global_load_lds staging, XOR-swizzled LDS, 48 MFMA : 16 ds_read per k-step.
// EPI 0: qkv scatter (q f32 | kh/kl [bh][key][d] | vth/vtl [bh][d][key])
// EPI 1: +bias +res -> Cf f32     EPI 2: +bias, GELU -> Ch/Cl bf16
// EPI 3: +bias +res -> Cf f32
// ---------------------------------------------------------------------------
template <int EPI>
__global__ __launch_bounds__(256, 2) void sgemm_k(
    const u16* __restrict__ Ah, const u16* __restrict__ Al,
    const u16* __restrict__ Bh, const u16* __restrict__ Bl,
    const float* __restrict__ bias, const float* __restrict__ res,
    float* __restrict__ Cf, u16* __restrict__ Ch, u16* __restrict__ Cl,
    u16* __restrict__ Dh, u16* __restrict__ Dl,
    int M, int N, int K) {
    __shared__ u16 sm[4][4096];  // Ah | Al | Bh | Bl tiles: [r*32 + pos*8]
    const int tid = threadIdx.x;
    const int lane = tid & 63, wv = tid >> 6;
    const int col = lane & 15, quad = lane >> 4;
    const int wm = (wv & 1) << 6, wn = (wv >> 1) << 6;
    const int bm = blockIdx.y << 7, bn = blockIdx.x << 7;

    // staging: thread covers chunk G0=tid and G1=tid+256 of each 512-chunk tile
    const int r0 = tid >> 2,         c0 = (tid & 3) ^ ((r0 >> 1) & 3);
    const int r1 = (tid + 256) >> 2, c1 = (tid & 3) ^ ((r1 >> 1) & 3);
    const u16* Ag0 = Ah + (size_t)(bm + r0) * K + c0 * 8;
    const u16* Ag1 = Ah + (size_t)(bm + r1) * K + c1 * 8;
    const u16* ALg0 = Al + (size_t)(bm + r0) * K + c0 * 8;
    const u16* ALg1 = Al + (size_t)(bm + r1) * K + c1 * 8;
    const u16* Bg0 = Bh + (size_t)(bn + r0) * K + c0 * 8;
    const u16* Bg1 = Bh + (size_t)(bn + r1) * K + c1 * 8;
    const u16* BLg0 = Bl + (size_t)(bn + r0) * K + c0 * 8;
    const u16* BLg1 = Bl + (size_t)(bn + r1) * K + c1 * 8;
    u16* l0 = &sm[0][wv * 512];        // this wave's first 64-chunk slot
    u16* l1 = &sm[0][wv * 512 + 2048]; // second slot (+256 chunks)
    const int swz = (col >> 1) & 3;
    const f32x4 z4 = {0.f, 0.f, 0.f, 0.f};
    f32x4 acc[4][4] = {{z4,z4,z4,z4},{z4,z4,z4,z4},{z4,z4,z4,z4},{z4,z4,z4,z4}};

    for (int k0 = 0; k0 < K; k0 += 32) {
        __syncthreads();
        a16(l0,          Ag0 + k0);  a16(l1,          Ag1 + k0);
        a16(l0 + 4096,   ALg0 + k0); a16(l1 + 4096,   ALg1 + k0);
        a16(l0 + 8192,   Bg0 + k0);  a16(l1 + 8192,   Bg1 + k0);
        a16(l0 + 12288,  BLg0 + k0); a16(l1 + 12288,  BLg1 + k0);
        __syncthreads();
        bf16x8 af[4][2];
#pragma unroll
        for (int mt = 0; mt < 4; mt++) {
            const int ra = (wm + (mt << 4) + col) * 32 + ((quad ^ swz) << 3);
            af[mt][0] = *(const bf16x8*)&sm[0][ra];
            af[mt][1] = *(const bf16x8*)&sm[1][ra];
        }
#pragma unroll
        for (int nt = 0; nt < 4; nt++) {
            const int rb = (wn + (nt << 4) + col) * 32 + ((quad ^ swz) << 3);
            bf16x8 bh_ = *(const bf16x8*)&sm[2][rb];
            bf16x8 bl_ = *(const bf16x8*)&sm[3][rb];
#pragma unroll
            for (int mt = 0; mt < 4; mt++) {
                acc[mt][nt] = __builtin_amdgcn_mfma_f32_16x16x32_bf16(af[mt][0], bh_, acc[mt][nt], 0, 0, 0);
                acc[mt][nt] = __builtin_amdgcn_mfma_f32_16x16x32_bf16(af[mt][0], bl_, acc[mt][nt], 0, 0, 0);
                acc[mt][nt] = __builtin_amdgcn_mfma_f32_16x16x32_bf16(af[mt][1], bh_, acc[mt][nt], 0, 0, 0);
            }
        }
    }

    // epilogue: C row = bm+wm+mt*16+quad*4+rr, col = bn+wn+nt*16+col
    float bs[4];
    if constexpr (EPI >= 1) {
#pragma unroll
        for (int nt = 0; nt < 4; nt++) bs[nt] = bias[bn + wn + (nt << 4) + col];
    }
#pragma unroll
    for (int mt = 0; mt < 4; mt++) {
#pragma unroll
        for (int rr = 0; rr < 4; rr++) {
            const int row = bm + wm + (mt << 4) + (quad << 2) + rr;
#pragma unroll
            for (int nt = 0; nt < 4; nt++) {
                const int colg = bn + wn + (nt << 4) + col;
                float v = acc[mt][nt][rr];
                if constexpr (EPI == 0) {
                    const int b = row >> 11, key = row & 2047;
                    if (bn < 512) {
                        Cf[((size_t)row << 9) + colg] = v;
                    } else if (bn < 1024) {
                        const int hd = (colg - 512) >> 6, d = colg & 63;
                        const size_t base = ((size_t)((b << 3) + hd) << 17) + (key << 6) + d;
                        u16 hi = f2bf(v);
                        Ch[base] = hi; Cl[base] = f2bf(v - bf2f(hi));
                    } else {
                        const int hd = (colg - 1024) >> 6, d = colg & 63;
                        const size_t base = ((size_t)((b << 3) + hd) << 17) + ((size_t)d << 11) + key;
                        u16 hi = f2bf(v);
                        Dh[base] = hi; Dl[base] = f2bf(v - bf2f(hi));
                    }
                } else if constexpr (EPI == 2) {
                    v = gelu_exact(v + bs[nt]);
                    const size_t o = (size_t)row * N + colg;
                    u16 hi = f2bf(v);
                    Ch[o] = hi; Cl[o] = f2bf(v - bf2f(hi));
                } else {
                    const size_t o = (size_t)row * N + colg;
                    Cf[o] = v + bs[nt] + res[o];
                }
            }
        }
    }
}

// ---------------------------------------------------------------------------
// Flash attention, split-bf16 MFMA, pre-split K/V staged via global_load_lds.
// Grid (32 q-tiles, 32 bh), 256 thr = 4 waves, wave owns 16 q rows.
// LDS 32KB: Kh[0,4096) Kl[4096,8192) Vh[8192,12288) Vl[12288,16384) (u16);
// P hi/lo overlays Kh/Kl after St reads complete. Row swizzle: pos = c^(r&7).
// ---------------------------------------------------------------------------
__global__ __launch_bounds__(256, 4) void attn_k(const float* __restrict__ q,
                                                 const u16* __restrict__ kh,
                                                 const u16* __restrict__ kl,
                                                 const u16* __restrict__ vth,
                                                 const u16* __restrict__ vtl,
                                                 u16* __restrict__ ah,
                                                 u16* __restrict__ al) {
    __shared__ u16 sm[16384];
    const int tid = threadIdx.x;
    const int lane = tid & 63, wv = tid >> 6;
    const int col = lane & 15, quad = lane >> 4;
    const int qt = blockIdx.x, bh = blockIdx.y;
    const int b = bh >> 3, h = bh & 7;
    const size_t tok0 = (size_t)b * SEQ;
    const size_t bhK = (size_t)bh << 17;
    const int q0 = qt << 6;

    // Q fragments (B-operand: n=q=col, k=d), 0.125 scale folded in.
    bf16x8 qfh[2], qfl[2];
    {
        const int qrow = q0 + (wv << 4) + col;
        const float* qp = q + ((tok0 + qrow) << 9) + (h << 6) + (quad << 3);
#pragma unroll
        for (int kc = 0; kc < 2; kc++) {
            float v[8];
            *(float4*)&v[0] = *(const float4*)(qp + (kc << 5));
            *(float4*)&v[4] = *(const float4*)(qp + (kc << 5) + 4);
            union { u16 us[8]; bf16x8 v8; } H, L;
#pragma unroll
            for (int i = 0; i < 8; i++) {
                float f = v[i] * 0.125f;
                u16 hi = f2bf(f);
                H.us[i] = hi;
                L.us[i] = f2bf(f - bf2f(hi));
            }
            qfh[kc] = H.v8; qfl[kc] = L.v8;
        }
    }

    const f32x4 z4 = {0.f, 0.f, 0.f, 0.f};
    f32x4 o[4] = {z4, z4, z4, z4};
    float m_run = -1e30f, l_run = 0.0f;

    // staging map: thread covers chunks G=(wv*2+jj)*64+lane, jj=0,1
    const int G0 = (wv << 1) * 64 + lane, G1 = G0 + 64;
    const int sr0 = G0 >> 3, sp0 = (G0 & 7) ^ (sr0 & 7);
    const int sr1 = G1 >> 3, sp1 = (G1 & 7) ^ (sr1 & 7);
    u16* lb0 = &sm[(size_t)(wv << 1) * 512];
    u16* lb1 = lb0 + 512;
    const size_t kg0 = bhK + ((size_t)sr0 << 6) + (sp0 << 3);  // + jt*64*64
    const size_t kg1 = bhK + ((size_t)sr1 << 6) + (sp1 << 3);
    const size_t vg0 = bhK + ((size_t)sr0 << 11) + (sp0 << 3); // + jt*64
    const size_t vg1 = bhK + ((size_t)sr1 << 11) + (sp1 << 3);

    for (int jt = 0; jt < 32; jt++) {
        __syncthreads();  // prior P/V reads complete
        {
            const size_t ko = (size_t)(jt << 6) << 6, vo = (size_t)(jt << 6);
            a16(lb0,          kh + kg0 + ko);  a16(lb1,          kh + kg1 + ko);
            a16(lb0 + 4096,   kl + kg0 + ko);  a16(lb1 + 4096,   kl + kg1 + ko);
            a16(lb0 + 8192,   vth + vg0 + vo); a16(lb1 + 8192,   vth + vg1 + vo);
            a16(lb0 + 12288,  vtl + vg0 + vo); a16(lb1 + 12288,  vtl + vg1 + vo);
        }
        __syncthreads();

        // ---- St[key][q] = K · Qᵀ ----
        f32x4 st[4] = {z4, z4, z4, z4};
#pragma unroll
        for (int kb = 0; kb < 4; kb++) {
            const int key = (kb << 4) + col;
            const int r64 = key << 6, k7 = key & 7;
#pragma unroll
            for (int kc = 0; kc < 2; kc++) {
                const int ofs = r64 + ((((kc << 2) + quad) ^ k7) << 3);
                bf16x8 khf = *(const bf16x8*)&sm[ofs];
                bf16x8 klf = *(const bf16x8*)&sm[4096 + ofs];
                st[kb] = __builtin_amdgcn_mfma_f32_16x16x32_bf16(khf, qfh[kc], st[kb], 0, 0, 0);
                st[kb] = __builtin_amdgcn_mfma_f32_16x16x32_bf16(khf, qfl[kc], st[kb], 0, 0, 0);
                st[kb] = __builtin_amdgcn_mfma_f32_16x16x32_bf16(klf, qfh[kc], st[kb], 0, 0, 0);
            }
        }

        // ---- online softmax (lane owns q=col; 16 keys local) ----
        float mx = st[0][0];
#pragma unroll
        for (int kb = 0; kb < 4; kb++)
#pragma unroll
            for (int r = 0; r < 4; r++) mx = fmaxf(mx, st[kb][r]);
        mx = fmaxf(mx, __shfl_xor(mx, 16));
        mx = fmaxf(mx, __shfl_xor(mx, 32));
        const float mn = fmaxf(m_run, mx);
        const float alp = __expf(m_run - mn);
        m_run = mn;
        float p[16];
        float rs = 0.0f;
#pragma unroll
        for (int kb = 0; kb < 4; kb++)
#pragma unroll
            for (int r = 0; r < 4; r++) {
                float e = __expf(st[kb][r] - mn);
                p[(kb << 2) + r] = e;
                rs += e;
            }
        rs += __shfl_xor(rs, 16);
        rs += __shfl_xor(rs, 32);
        l_run = l_run * alp + rs;
        float aO[4];
#pragma unroll
        for (int r = 0; r < 4; r++) aO[r] = __shfl(alp, (quad << 2) + r);
#pragma unroll
        for (int db = 0; db < 4; db++) {
            o[db][0] *= aO[0]; o[db][1] *= aO[1];
            o[db][2] *= aO[2]; o[db][3] *= aO[3];
        }

        __syncthreads();  // all K reads done -> P may overwrite Kh/Kl
        // ---- P -> LDS (row-major P[q][key], swizzled) ----
        const int prow = (wv << 4) + col;
        const int p64 = prow << 6, p7 = prow & 7;
#pragma unroll
        for (int kb = 0; kb < 4; kb++) {
            u16x4 hv, lv;
#pragma unroll
            for (int r = 0; r < 4; r++) {
                float e = p[(kb << 2) + r];
                u16 hi = f2bf(e);
                hv[r] = hi;
                lv[r] = f2bf(e - bf2f(hi));
            }
            const int c = (kb << 1) + (quad >> 1);
            const int ofs = p64 + ((c ^ p7) << 3) + ((quad & 1) << 2);
            *(u16x4*)&sm[ofs]        = hv;
            *(u16x4*)&sm[4096 + ofs] = lv;
        }
        // wave-private rows: DS pipe is in-order per wave, no barrier needed
        bf16x8 pfh[2], pfl[2];
#pragma unroll
        for (int kc = 0; kc < 2; kc++) {
            const int ofs = p64 + ((((kc << 2) + quad) ^ p7) << 3);
            pfh[kc] = *(const bf16x8*)&sm[ofs];
            pfl[kc] = *(const bf16x8*)&sm[4096 + ofs];
        }
        // ---- O += P · V ----
#pragma unroll
        for (int db = 0; db < 4; db++) {
            const int d = (db << 4) + col;
            const int v64 = 8192 + (d << 6), d7 = d & 7;
#pragma unroll
            for (int kc = 0; kc < 2; kc++) {
                const int ofs = v64 + ((((kc << 2) + quad) ^ d7) << 3);
                bf16x8 vh = *(const bf16x8*)&sm[ofs];
                bf16x8 vl = *(const bf16x8*)&sm[4096 + ofs];
                o[db] = __builtin_amdgcn_mfma_f32_16x16x32_bf16(pfh[kc], vh, o[db], 0, 0, 0);
                o[db] = __builtin_amdgcn_mfma_f32_16x16x32_bf16(pfh[kc], vl, o[db], 0, 0, 0);
                o[db] = __builtin_amdgcn_mfma_f32_16x16x32_bf16(pfl[kc], vh, o[db], 0, 0, 0);
            }
        }
    }

    // ---- epilogue: O/l -> split bf16 attended [tok][h*64+d] ----
    float linv[4];
#pragma unroll
    for (int r = 0; r < 4; r++) linv[r] = 1.0f / __shfl(l_run, (quad << 2) + r);
#pragma unroll
    for (int r = 0; r < 4; r++) {
        const size_t rowo = ((tok0 + q0 + (wv << 4) + (quad << 2) + r) << 9) + (h << 6) + col;
#pragma unroll
        for (int db = 0; db < 4; db++) {
            float v = o[db][r] * linv[r];
            u16 hi = f2bf(v);
            ah[rowo + (db << 4)] = hi;
            al[rowo + (db << 4)] = f2bf(v - bf2f(hi));
        }
    }
}

// ---------------------------------------------------------------------------
extern "C" void kernel_launch(void* const* d_in, const int* in_sizes, int n_in,
                              void* d_out, int out_size, void* d_ws, size_t ws_size,
                              hipStream_t stream) {
    const float* x     = (const float*)d_in[0];
    const float* ln1_g = (const float*)d_in[1];
    const float* ln1_b = (const float*)d_in[2];
    const float* w_qkv = (const float*)d_in[3];
    const float* w_out = (const float*)d_in[4];
    const float* b_out = (const float*)d_in[5];
    const float* ln2_g = (const float*)d_in[6];
    const float* ln2_b = (const float*)d_in[7];
    const float* w1    = (const float*)d_in[8];
    const float* b1    = (const float*)d_in[9];
    const float* w2    = (const float*)d_in[10];
    const float* b2    = (const float*)d_in[11];
    float* out = (float*)d_out;

    u16* wqkvh = (u16*)d_ws;                       // [1536][512]
    u16* wqkvl = wqkvh + 1536 * 512;
    u16* wouth = wqkvl + 1536 * 512;               // [512][512]
    u16* woutl = wouth + 512 * 512;
    u16* w1h   = woutl + 512 * 512;                // [1024][512]
    u16* w1l   = w1h + 1024 * 512;
    u16* w2h   = w1l + 1024 * 512;                 // [512][1024]
    u16* w2l   = w2h + 512 * 1024;
    u16* R1    = w2l + 512 * 1024;                 // h / attended / h2 (hi,lo)
    u16* hh = R1, *hl = R1 + (size_t)TOKENS * 512;
    float* R2  = (float*)(R1 + (size_t)2 * TOKENS * 512);  // q -> x2
    float* qbuf = R2, *x2 = R2;
    u16* R3  = (u16*)(R2 + (size_t)TOKENS * 512);
    u16* kh  = R3;                                 // [32][2048][64]
    u16* kl  = kh + (size_t)32 * 131072;
    u16* vth = kl + (size_t)32 * 131072;           // [32][64][2048]
    u16* vtl = vth + (size_t)32 * 131072;
    u16* gh  = R3, *gl = R3 + (size_t)TOKENS * 1024;  // gelu out (aliases k/v)

    wtconv_k<<<dim3(24, 8), 256, 0, stream>>>(w_qkv, wqkvh, wqkvl, 512, 1536);
    wtconv_k<<<dim3(8, 8),  256, 0, stream>>>(w_out, wouth, woutl, 512, 512);
    wtconv_k<<<dim3(16, 8), 256, 0, stream>>>(w1, w1h, w1l, 512, 1024);
    wtconv_k<<<dim3(8, 16), 256, 0, stream>>>(w2, w2h, w2l, 1024, 512);

    ln_k<<<TOKENS / 4, 256, 0, stream>>>(x, ln1_g, ln1_b, hh, hl);
    sgemm_k<0><<<dim3(12, 64), 256, 0, stream>>>(hh, hl, wqkvh, wqkvl, nullptr, nullptr,
                                                 qbuf, kh, kl, vth, vtl, TOKENS, 1536, 512);
    attn_k<<<dim3(32, 32), 256, 0, stream>>>(qbuf, kh, kl, vth, vtl, hh, hl);
    sgemm_k<1><<<dim3(4, 64), 256, 0, stream>>>(hh, hl, wouth, woutl, b_out, x,
                                                x2, nullptr, nullptr, nullptr, nullptr,
                                                TOKENS, 512, 512);
    ln_k<<<TOKENS / 4, 256, 0, stream>>>(x2, ln2_g, ln2_b, hh, hl);
    sgemm_k<2><<<dim3(8, 64), 256, 0, stream>>>(hh, hl, w1h, w1l, b1, nullptr,
                                                nullptr, gh, gl, nullptr, nullptr,
                                                TOKENS, 1024, 512);
    sgemm_k<3><<<dim3(4, 64), 256, 0, stream>>>(gh, gl, w2h, w2l, b2, x2,
                                                out, nullptr, nullptr, nullptr, nullptr,
                                                TOKENS, 512, 1024);
}

// Round 4
// 401.547 us; speedup vs baseline: 4.5377x; 1.0535x over previous
//
#include <hip/hip_runtime.h>
#include <math.h>

// TransformerBlock for MI355X — round 4: attention LDS-traffic cut
// (2 q-subtiles per wave; K/V LDS reads amortized 2x; P region disjoint,
// 2 barriers/jt). GEMMs unchanged from round 3 (counters next round).
// ws layout (75.5 MB):
//   W  [0, 8.39M)        : wqkvT h/l | woutT h/l | w1T h/l | w2T h/l  (bf16, [N][K])
//   R1 [8.39M, 25.2M)    : h hi/lo -> attended hi/lo -> h2 hi/lo   (8192*512 u16 x2)
//   R2 [25.2M, 41.9M)    : q fp32 -> x2 fp32                       (8192*512 f32)
//   R3 [41.9M, 75.5M)    : kh|kl|vth|vtl (bf16) -> gh|gl           (33.55M)

#define TOKENS 8192
#define SEQ    2048
typedef unsigned short u16;
typedef __attribute__((ext_vector_type(8))) short bf16x8;
typedef __attribute__((ext_vector_type(4))) float f32x4;
typedef __attribute__((ext_vector_type(4))) unsigned short u16x4;

__device__ __forceinline__ u16 f2bf(float f) {
    unsigned u = __builtin_bit_cast(unsigned, f);
    u += 0x7fffu + ((u >> 16) & 1u);
    return (u16)(u >> 16);
}
__device__ __forceinline__ float bf2f(u16 h) {
    unsigned u = ((unsigned)h) << 16;
    return __builtin_bit_cast(float, u);
}
__device__ __forceinline__ void a16(void* lds, const void* g) {
    __builtin_amdgcn_global_load_lds(
        (const __attribute__((address_space(1))) unsigned int*)g,
        (__attribute__((address_space(3))) unsigned int*)lds, 16, 0, 0);
}
__device__ __forceinline__ float gelu_exact(float v) {
    return 0.5f * v * (1.0f + erff(v * 0.70710678118654752f));
}

// ---------------------------------------------------------------------------
// LayerNorm -> split bf16 hi/lo. One wave per 512-f32 row, block = 4 rows.
// ---------------------------------------------------------------------------
__global__ __launch_bounds__(256) void ln_k(const float* __restrict__ x,
                                            const float* __restrict__ g,
                                            const float* __restrict__ bta,
                                            u16* __restrict__ oh,
                                            u16* __restrict__ ol) {
    const int lane = threadIdx.x & 63;
    const int row  = (blockIdx.x << 2) + (threadIdx.x >> 6);
    const float* xr = x + ((size_t)row << 9) + (lane << 3);
    float v[8];
    *(float4*)&v[0] = *(const float4*)xr;
    *(float4*)&v[4] = *(const float4*)(xr + 4);
    float s = 0.f, ss = 0.f;
#pragma unroll
    for (int i = 0; i < 8; i++) { s += v[i]; ss += v[i] * v[i]; }
#pragma unroll
    for (int m = 32; m; m >>= 1) {
        s  += __shfl_xor(s, m, 64);
        ss += __shfl_xor(ss, m, 64);
    }
    const float mu   = s * (1.0f / 512.0f);
    const float rstd = rsqrtf(ss * (1.0f / 512.0f) - mu * mu + 1e-5f);
    float gg[8], bb[8];
    *(float4*)&gg[0] = *(const float4*)(g + (lane << 3));
    *(float4*)&gg[4] = *(const float4*)(g + (lane << 3) + 4);
    *(float4*)&bb[0] = *(const float4*)(bta + (lane << 3));
    *(float4*)&bb[4] = *(const float4*)(bta + (lane << 3) + 4);
    union { u16 us[8]; uint4 q; } H, L;
#pragma unroll
    for (int i = 0; i < 8; i++) {
        float r = (v[i] - mu) * rstd * gg[i] + bb[i];
        u16 hi = f2bf(r);
        H.us[i] = hi;
        L.us[i] = f2bf(r - bf2f(hi));
    }
    const size_t o = ((size_t)row << 9) + (lane << 3);
    *(uint4*)&oh[o] = H.q;
    *(uint4*)&ol[o] = L.q;
}

// ---------------------------------------------------------------------------
// Weight transpose+split: src[K][N] f32 -> dh/dl[N][K] bf16. Grid (N/64,K/64).
// ---------------------------------------------------------------------------
__global__ __launch_bounds__(256) void wtconv_k(const float* __restrict__ src,
                                                u16* __restrict__ dh,
                                                u16* __restrict__ dl,
                                                int K, int N) {
    __shared__ float t[64][65];
    const int tid = threadIdx.x;
    const int n0 = blockIdx.x << 6, k0 = blockIdx.y << 6;
    {
        const int kr = tid >> 2, nc = (tid & 3) << 4;
        const float* p = src + (size_t)(k0 + kr) * N + n0 + nc;
#pragma unroll
        for (int i = 0; i < 4; i++)
            *(float4*)&t[kr][nc + (i << 2)] = *(const float4*)(p + (i << 2));
    }
    __syncthreads();
    {
        const int nr = tid >> 2, kc = (tid & 3) << 4;
        union { u16 us[16]; uint4 q[2]; } H, L;
#pragma unroll
        for (int i = 0; i < 16; i++) {
            float f = t[kc + i][nr];
            u16 hi = f2bf(f);
            H.us[i] = hi;
            L.us[i] = f2bf(f - bf2f(hi));
        }
        const size_t o = (size_t)(n0 + nr) * K + k0 + kc;
        *(uint4*)&dh[o] = H.q[0]; *(uint4*)&dh[o + 8] = H.q[1];
        *(uint4*)&dl[o] = L.q[0]; *(uint4*)&dl[o + 8] = L.q[1];
    }
}

// ---------------------------------------------------------------------------
// Split-bf16 MFMA GEMM: C[M,N] = A[M,K]B[K,N], A as Ah/Al [M][K] bf16,
// B as Bh/Bl [N][K] bf16 (pre-transposed). 128x128 tile, BK=32, 4 waves 2x2,
// global_load_lds staging, XOR-swizzled LDS, 48 MFMA : 16 ds_read per k-step.
// EPI 0: qkv scatter (q f32 | kh/kl [bh][key][d] | vth/vtl [bh][d][key])
// EPI 1: +bias +res -> Cf f32     EPI 2: +bias, GELU -> Ch/Cl bf16
// EPI 3: +bias +res -> Cf f32
// ---------------------------------------------------------------------------
template <int EPI>
__global__ __launch_bounds__(256, 2) void sgemm_k(
    const u16* __restrict__ Ah, const u16* __restrict__ Al,
    const u16* __restrict__ Bh, const u16* __restrict__ Bl,
    const float* __restrict__ bias, const float* __restrict__ res,
    float* __restrict__ Cf, u16* __restrict__ Ch, u16* __restrict__ Cl,
    u16* __restrict__ Dh, u16* __restrict__ Dl,
    int M, int N, int K) {
    __shared__ u16 sm[4][4096];  // Ah | Al | Bh | Bl tiles: [r*32 + pos*8]
    const int tid = threadIdx.x;
    const int lane = tid & 63, wv = tid >> 6;
    const int col = lane & 15, quad = lane >> 4;
    const int wm = (wv & 1) << 6, wn = (wv >> 1) << 6;
    const int bm = blockIdx.y << 7, bn = blockIdx.x << 7;

    const int r0 = tid >> 2,         c0 = (tid & 3) ^ ((r0 >> 1) & 3);
    const int r1 = (tid + 256) >> 2, c1 = (tid & 3) ^ ((r1 >> 1) & 3);
    const u16* Ag0 = Ah + (size_t)(bm + r0) * K + c0 * 8;
    const u16* Ag1 = Ah + (size_t)(bm + r1) * K + c1 * 8;
    const u16* ALg0 = Al + (size_t)(bm + r0) * K + c0 * 8;
    const u16* ALg1 = Al + (size_t)(bm + r1) * K + c1 * 8;
    const u16* Bg0 = Bh + (size_t)(bn + r0) * K + c0 * 8;
    const u16* Bg1 = Bh + (size_t)(bn + r1) * K + c1 * 8;
    const u16* BLg0 = Bl + (size_t)(bn + r0) * K + c0 * 8;
    const u16* BLg1 = Bl + (size_t)(bn + r1) * K + c1 * 8;
    u16* l0 = &sm[0][wv * 512];
    u16* l1 = &sm[0][wv * 512 + 2048];
    const int swz = (col >> 1) & 3;
    const f32x4 z4 = {0.f, 0.f, 0.f, 0.f};
    f32x4 acc[4][4] = {{z4,z4,z4,z4},{z4,z4,z4,z4},{z4,z4,z4,z4},{z4,z4,z4,z4}};

    for (int k0 = 0; k0 < K; k0 += 32) {
        __syncthreads();
        a16(l0,          Ag0 + k0);  a16(l1,          Ag1 + k0);
        a16(l0 + 4096,   ALg0 + k0); a16(l1 + 4096,   ALg1 + k0);
        a16(l0 + 8192,   Bg0 + k0);  a16(l1 + 8192,   Bg1 + k0);
        a16(l0 + 12288,  BLg0 + k0); a16(l1 + 12288,  BLg1 + k0);
        __syncthreads();
        bf16x8 af[4][2];
#pragma unroll
        for (int mt = 0; mt < 4; mt++) {
            const int ra = (wm + (mt << 4) + col) * 32 + ((quad ^ swz) << 3);
            af[mt][0] = *(const bf16x8*)&sm[0][ra];
            af[mt][1] = *(const bf16x8*)&sm[1][ra];
        }
#pragma unroll
        for (int nt = 0; nt < 4; nt++) {
            const int rb = (wn + (nt << 4) + col) * 32 + ((quad ^ swz) << 3);
            bf16x8 bh_ = *(const bf16x8*)&sm[2][rb];
            bf16x8 bl_ = *(const bf16x8*)&sm[3][rb];
#pragma unroll
            for (int mt = 0; mt < 4; mt++) {
                acc[mt][nt] = __builtin_amdgcn_mfma_f32_16x16x32_bf16(af[mt][0], bh_, acc[mt][nt], 0, 0, 0);
                acc[mt][nt] = __builtin_amdgcn_mfma_f32_16x16x32_bf16(af[mt][0], bl_, acc[mt][nt], 0, 0, 0);
                acc[mt][nt] = __builtin_amdgcn_mfma_f32_16x16x32_bf16(af[mt][1], bh_, acc[mt][nt], 0, 0, 0);
            }
        }
    }

    float bs[4];
    if constexpr (EPI >= 1) {
#pragma unroll
        for (int nt = 0; nt < 4; nt++) bs[nt] = bias[bn + wn + (nt << 4) + col];
    }
#pragma unroll
    for (int mt = 0; mt < 4; mt++) {
#pragma unroll
        for (int rr = 0; rr < 4; rr++) {
            const int row = bm + wm + (mt << 4) + (quad << 2) + rr;
#pragma unroll
            for (int nt = 0; nt < 4; nt++) {
                const int colg = bn + wn + (nt << 4) + col;
                float v = acc[mt][nt][rr];
                if constexpr (EPI == 0) {
                    const int b = row >> 11, key = row & 2047;
                    if (bn < 512) {
                        Cf[((size_t)row << 9) + colg] = v;
                    } else if (bn < 1024) {
                        const int hd = (colg - 512) >> 6, d = colg & 63;
                        const size_t base = ((size_t)((b << 3) + hd) << 17) + (key << 6) + d;
                        u16 hi = f2bf(v);
                        Ch[base] = hi; Cl[base] = f2bf(v - bf2f(hi));
                    } else {
                        const int hd = (colg - 1024) >> 6, d = colg & 63;
                        const size_t base = ((size_t)((b << 3) + hd) << 17) + ((size_t)d << 11) + key;
                        u16 hi = f2bf(v);
                        Dh[base] = hi; Dl[base] = f2bf(v - bf2f(hi));
                    }
                } else if constexpr (EPI == 2) {
                    v = gelu_exact(v + bs[nt]);
                    const size_t o = (size_t)row * N + colg;
                    u16 hi = f2bf(v);
                    Ch[o] = hi; Cl[o] = f2bf(v - bf2f(hi));
                } else {
                    const size_t o = (size_t)row * N + colg;
                    Cf[o] = v + bs[nt] + res[o];
                }
            }
        }
    }
}

// ---------------------------------------------------------------------------
// Flash attention, split-bf16 MFMA, 2 q-subtiles per wave (32 q-rows/wave,
// 128 q-rows/block). Grid (16 q-tiles, 32 bh), 256 thr = 4 waves.
// LDS 64KB (u16 idx): Kh[0,4K) Kl[4K,8K) Vh[8K,12K) Vl[12K,16K)
//                     Ph[16K,24K) Pl[24K,32K)   (P rows wave-private)
// K/V fragments are sub-invariant -> each LDS read feeds 2x MFMA.
// 2 barriers per jt (P region disjoint from K/V).
// ---------------------------------------------------------------------------
__global__ __launch_bounds__(256, 2) void attn_k(const float* __restrict__ q,
                                                 const u16* __restrict__ kh,
                                                 const u16* __restrict__ kl,
                                                 const u16* __restrict__ vth,
                                                 const u16* __restrict__ vtl,
                                                 u16* __restrict__ ah,
                                                 u16* __restrict__ al) {
    __shared__ u16 sm[32768];
    const int tid = threadIdx.x;
    const int lane = tid & 63, wv = tid >> 6;
    const int col = lane & 15, quad = lane >> 4;
    const int qt = blockIdx.x, bh = blockIdx.y;
    const int b = bh >> 3, h = bh & 7;
    const size_t tok0 = (size_t)b * SEQ;
    const size_t bhK = (size_t)bh << 17;
    const int q0 = qt << 7;

    // Q fragments for both subtiles (B-operand; 0.125 scale folded in).
    bf16x8 qfh[2][2], qfl[2][2];
#pragma unroll
    for (int sub = 0; sub < 2; sub++) {
        const int qrow = q0 + (wv << 5) + (sub << 4) + col;
        const float* qp = q + ((tok0 + qrow) << 9) + (h << 6) + (quad << 3);
#pragma unroll
        for (int kc = 0; kc < 2; kc++) {
            float v[8];
            *(float4*)&v[0] = *(const float4*)(qp + (kc << 5));
            *(float4*)&v[4] = *(const float4*)(qp + (kc << 5) + 4);
            union { u16 us[8]; bf16x8 v8; } H, L;
#pragma unroll
            for (int i = 0; i < 8; i++) {
                float f = v[i] * 0.125f;
                u16 hi = f2bf(f);
                H.us[i] = hi;
                L.us[i] = f2bf(f - bf2f(hi));
            }
            qfh[sub][kc] = H.v8; qfl[sub][kc] = L.v8;
        }
    }

    const f32x4 z4 = {0.f, 0.f, 0.f, 0.f};
    f32x4 o[2][4] = {{z4, z4, z4, z4}, {z4, z4, z4, z4}};
    float m_run[2] = {-1e30f, -1e30f}, l_run[2] = {0.f, 0.f};

    // staging map: thread covers chunks G0=wv*128+lane, G1=G0+64 (512 chunks)
    const int G0 = (wv << 7) + lane, G1 = G0 + 64;
    const int sr0 = G0 >> 3, sp0 = (G0 & 7) ^ (sr0 & 7);
    const int sr1 = G1 >> 3, sp1 = (G1 & 7) ^ (sr1 & 7);
    u16* lb0 = &sm[(size_t)(wv << 10)];
    u16* lb1 = lb0 + 512;
    const size_t kg0 = bhK + ((size_t)sr0 << 6) + (sp0 << 3);  // + jt*64*64
    const size_t kg1 = bhK + ((size_t)sr1 << 6) + (sp1 << 3);
    const size_t vg0 = bhK + ((size_t)sr0 << 11) + (sp0 << 3); // + jt*64
    const size_t vg1 = bhK + ((size_t)sr1 << 11) + (sp1 << 3);

    for (int jt = 0; jt < 32; jt++) {
        __syncthreads();  // prior jt's K/V reads complete
        {
            const size_t ko = (size_t)(jt << 6) << 6, vo = (size_t)(jt << 6);
            a16(lb0,          kh + kg0 + ko);  a16(lb1,          kh + kg1 + ko);
            a16(lb0 + 4096,   kl + kg0 + ko);  a16(lb1 + 4096,   kl + kg1 + ko);
            a16(lb0 + 8192,   vth + vg0 + vo); a16(lb1 + 8192,   vth + vg1 + vo);
            a16(lb0 + 12288,  vtl + vg0 + vo); a16(lb1 + 12288,  vtl + vg1 + vo);
        }
        __syncthreads();

        // ---- St[key][q] = K · Qᵀ for both subtiles (K frags read once) ----
        f32x4 st0[4] = {z4, z4, z4, z4}, st1[4] = {z4, z4, z4, z4};
#pragma unroll
        for (int kb = 0; kb < 4; kb++) {
            const int key = (kb << 4) + col;
            const int r64 = key << 6, k7 = key & 7;
#pragma unroll
            for (int kc = 0; kc < 2; kc++) {
                const int ofs = r64 + ((((kc << 2) + quad) ^ k7) << 3);
                bf16x8 khf = *(const bf16x8*)&sm[ofs];
                bf16x8 klf = *(const bf16x8*)&sm[4096 + ofs];
                st0[kb] = __builtin_amdgcn_mfma_f32_16x16x32_bf16(khf, qfh[0][kc], st0[kb], 0, 0, 0);
                st0[kb] = __builtin_amdgcn_mfma_f32_16x16x32_bf16(khf, qfl[0][kc], st0[kb], 0, 0, 0);
                st0[kb] = __builtin_amdgcn_mfma_f32_16x16x32_bf16(klf, qfh[0][kc], st0[kb], 0, 0, 0);
                st1[kb] = __builtin_amdgcn_mfma_f32_16x16x32_bf16(khf, qfh[1][kc], st1[kb], 0, 0, 0);
                st1[kb] = __builtin_amdgcn_mfma_f32_16x16x32_bf16(khf, qfl[1][kc], st1[kb], 0, 0, 0);
                st1[kb] = __builtin_amdgcn_mfma_f32_16x16x32_bf16(klf, qfh[1][kc], st1[kb], 0, 0, 0);
            }
        }

        // ---- online softmax + P->LDS per subtile ----
#pragma unroll
        for (int sub = 0; sub < 2; sub++) {
            f32x4* st = sub ? st1 : st0;
            float mx = st[0][0];
#pragma unroll
            for (int kb = 0; kb < 4; kb++)
#pragma unroll
                for (int r = 0; r < 4; r++) mx = fmaxf(mx, st[kb][r]);
            mx = fmaxf(mx, __shfl_xor(mx, 16));
            mx = fmaxf(mx, __shfl_xor(mx, 32));
            const float mn = fmaxf(m_run[sub], mx);
            const float alp = __expf(m_run[sub] - mn);
            m_run[sub] = mn;
            float p[16];
            float rs = 0.0f;
#pragma unroll
            for (int kb = 0; kb < 4; kb++)
#pragma unroll
                for (int r = 0; r < 4; r++) {
                    float e = __expf(st[kb][r] - mn);
                    p[(kb << 2) + r] = e;
                    rs += e;
                }
            rs += __shfl_xor(rs, 16);
            rs += __shfl_xor(rs, 32);
            l_run[sub] = l_run[sub] * alp + rs;
            float aO[4];
#pragma unroll
            for (int r = 0; r < 4; r++) aO[r] = __shfl(alp, (quad << 2) + r);
#pragma unroll
            for (int db = 0; db < 4; db++) {
                o[sub][db][0] *= aO[0]; o[sub][db][1] *= aO[1];
                o[sub][db][2] *= aO[2]; o[sub][db][3] *= aO[3];
            }
            // P (hi trunc, lo RTNE of remainder) -> LDS row-major, swizzled
            const int prow = (wv << 5) + (sub << 4) + col;
            const int p64 = prow << 6, p7 = prow & 7;
#pragma unroll
            for (int kb = 0; kb < 4; kb++) {
                u16x4 hv, lv;
#pragma unroll
                for (int r = 0; r < 4; r++) {
                    float e = p[(kb << 2) + r];
                    unsigned eu = __builtin_bit_cast(unsigned, e);
                    u16 hi = (u16)(eu >> 16);
                    hv[r] = hi;
                    lv[r] = f2bf(e - bf2f(hi));
                }
                const int c = (kb << 1) + (quad >> 1);
                const int ofs = p64 + ((c ^ p7) << 3) + ((quad & 1) << 2);
                *(u16x4*)&sm[16384 + ofs] = hv;
                *(u16x4*)&sm[24576 + ofs] = lv;
            }
        }

        // ---- P fragments (wave-private rows; same-wave RAW via lgkmcnt) ----
        bf16x8 pfh[2][2], pfl[2][2];
#pragma unroll
        for (int sub = 0; sub < 2; sub++) {
            const int prow = (wv << 5) + (sub << 4) + col;
            const int p64 = prow << 6, p7 = prow & 7;
#pragma unroll
            for (int kc = 0; kc < 2; kc++) {
                const int ofs = p64 + ((((kc << 2) + quad) ^ p7) << 3);
                pfh[sub][kc] = *(const bf16x8*)&sm[16384 + ofs];
                pfl[sub][kc] = *(const bf16x8*)&sm[24576 + ofs];
            }
        }

        // ---- O += P · V (V frags read once, feed both subtiles) ----
#pragma unroll
        for (int db = 0; db < 4; db++) {
            const int d = (db << 4) + col;
            const int v64 = 8192 + (d << 6), d7 = d & 7;
#pragma unroll
            for (int kc = 0; kc < 2; kc++) {
                const int ofs = v64 + ((((kc << 2) + quad) ^ d7) << 3);
                bf16x8 vh = *(const bf16x8*)&sm[ofs];
                bf16x8 vl = *(const bf16x8*)&sm[4096 + ofs];
                o[0][db] = __builtin_amdgcn_mfma_f32_16x16x32_bf16(pfh[0][kc], vh, o[0][db], 0, 0, 0);
                o[0][db] = __builtin_amdgcn_mfma_f32_16x16x32_bf16(pfh[0][kc], vl, o[0][db], 0, 0, 0);
                o[0][db] = __builtin_amdgcn_mfma_f32_16x16x32_bf16(pfl[0][kc], vh, o[0][db], 0, 0, 0);
                o[1][db] = __builtin_amdgcn_mfma_f32_16x16x32_bf16(pfh[1][kc], vh, o[1][db], 0, 0, 0);
                o[1][db] = __builtin_amdgcn_mfma_f32_16x16x32_bf16(pfh[1][kc], vl, o[1][db], 0, 0, 0);
                o[1][db] = __builtin_amdgcn_mfma_f32_16x16x32_bf16(pfl[1][kc], vh, o[1][db], 0, 0, 0);
            }
        }
    }

    // ---- epilogue: O/l -> split bf16 attended [tok][h*64+d] ----
#pragma unroll
    for (int sub = 0; sub < 2; sub++) {
        float linv[4];
#pragma unroll
        for (int r = 0; r < 4; r++) linv[r] = 1.0f / __shfl(l_run[sub], (quad << 2) + r);
#pragma unroll
        for (int r = 0; r < 4; r++) {
            const size_t rowo = ((tok0 + q0 + (wv << 5) + (sub << 4) + (quad << 2) + r) << 9)
                                + (h << 6) + col;
#pragma unroll
            for (int db = 0; db < 4; db++) {
                float v = o[sub][db][r] * linv[r];
                u16 hi = f2bf(v);
                ah[rowo + (db << 4)] = hi;
                al[rowo + (db << 4)] = f2bf(v - bf2f(hi));
            }
        }
    }
}

// ---------------------------------------------------------------------------
extern "C" void kernel_launch(void* const* d_in, const int* in_sizes, int n_in,
                              void* d_out, int out_size, void* d_ws, size_t ws_size,
                              hipStream_t stream) {
    const float* x     = (const float*)d_in[0];
    const float* ln1_g = (const float*)d_in[1];
    const float* ln1_b = (const float*)d_in[2];
    const float* w_qkv = (const float*)d_in[3];
    const float* w_out = (const float*)d_in[4];
    const float* b_out = (const float*)d_in[5];
    const float* ln2_g = (const float*)d_in[6];
    const float* ln2_b = (const float*)d_in[7];
    const float* w1    = (const float*)d_in[8];
    const float* b1    = (const float*)d_in[9];
    const float* w2    = (const float*)d_in[10];
    const float* b2    = (const float*)d_in[11];
    float* out = (float*)d_out;

    u16* wqkvh = (u16*)d_ws;                       // [1536][512]
    u16* wqkvl = wqkvh + 1536 * 512;
    u16* wouth = wqkvl + 1536 * 512;               // [512][512]
    u16* woutl = wouth + 512 * 512;
    u16* w1h   = woutl + 512 * 512;                // [1024][512]
    u16* w1l   = w1h + 1024 * 512;
    u16* w2h   = w1l + 1024 * 512;                 // [512][1024]
    u16* w2l   = w2h + 512 * 1024;
    u16* R1    = w2l + 512 * 1024;                 // h / attended / h2 (hi,lo)
    u16* hh = R1, *hl = R1 + (size_t)TOKENS * 512;
    float* R2  = (float*)(R1 + (size_t)2 * TOKENS * 512);  // q -> x2
    float* qbuf = R2, *x2 = R2;
    u16* R3  = (u16*)(R2 + (size_t)TOKENS * 512);
    u16* kh  = R3;                                 // [32][2048][64]
    u16* kl  = kh + (size_t)32 * 131072;
    u16* vth = kl + (size_t)32 * 131072;           // [32][64][2048]
    u16* vtl = vth + (size_t)32 * 131072;
    u16* gh  = R3, *gl = R3 + (size_t)TOKENS * 1024;  // gelu out (aliases k/v)

    wtconv_k<<<dim3(24, 8), 256, 0, stream>>>(w_qkv, wqkvh, wqkvl, 512, 1536);
    wtconv_k<<<dim3(8, 8),  256, 0, stream>>>(w_out, wouth, woutl, 512, 512);
    wtconv_k<<<dim3(16, 8), 256, 0, stream>>>(w1, w1h, w1l, 512, 1024);
    wtconv_k<<<dim3(8, 16), 256, 0, stream>>>(w2, w2h, w2l, 1024, 512);

    ln_k<<<TOKENS / 4, 256, 0, stream>>>(x, ln1_g, ln1_b, hh, hl);
    sgemm_k<0><<<dim3(12, 64), 256, 0, stream>>>(hh, hl, wqkvh, wqkvl, nullptr, nullptr,
                                                 qbuf, kh, kl, vth, vtl, TOKENS, 1536, 512);
    attn_k<<<dim3(16, 32), 256, 0, stream>>>(qbuf, kh, kl, vth, vtl, hh, hl);
    sgemm_k<1><<<dim3(4, 64), 256, 0, stream>>>(hh, hl, wouth, woutl, b_out, x,
                                                x2, nullptr, nullptr, nullptr, nullptr,
                                                TOKENS, 512, 512);
    ln_k<<<TOKENS / 4, 256, 0, stream>>>(x2, ln2_g, ln2_b, hh, hl);
    sgemm_k<2><<<dim3(8, 64), 256, 0, stream>>>(hh, hl, w1h, w1l, b1, nullptr,
                                                nullptr, gh, gl, nullptr, nullptr,
                                                TOKENS, 1024, 512);
    sgemm_k<3><<<dim3(4, 64), 256, 0, stream>>>(gh, gl, w2h, w2l, b2, x2,
                                                out, nullptr, nullptr, nullptr, nullptr,
                                                TOKENS, 512, 1024);
}

// Round 5
// 359.763 us; speedup vs baseline: 5.0647x; 1.1161x over previous
//
#include <hip/hip_runtime.h>
#include <math.h>

// TransformerBlock for MI355X — round 5.
// Precision-budgeted MFMA everywhere: activations exact-split (hi+lo bf16),
// weights / K / P single-rounded bf16 (err ~2^-10, budget allows).
// Attention: 128-thr blocks (2 waves x 2 q-subtiles), 32KB LDS, 4 blocks/CU.
// GEMMs: 2-term (Ah*Bh + Al*Bh), 24KB LDS.
// ws layout (~71 MB):
//   W  : wqkvT | woutT | w1T | w2T  (bf16 hi only, [N][K])
//   R1 : h hi/lo -> attended hi/lo -> h2 hi/lo   (8192*512 u16 x2)
//   R2 : q fp32 -> x2 fp32                       (8192*512 f32)
//   R3 : kh | vth | vtl (bf16) -> gh | gl        (33.5 MB)

#define TOKENS 8192
#define SEQ    2048
typedef unsigned short u16;
typedef __attribute__((ext_vector_type(8))) short bf16x8;
typedef __attribute__((ext_vector_type(4))) float f32x4;
typedef __attribute__((ext_vector_type(4))) unsigned short u16x4;

__device__ __forceinline__ u16 f2bf(float f) {
    unsigned u = __builtin_bit_cast(unsigned, f);
    u += 0x7fffu + ((u >> 16) & 1u);
    return (u16)(u >> 16);
}
__device__ __forceinline__ float bf2f(u16 h) {
    unsigned u = ((unsigned)h) << 16;
    return __builtin_bit_cast(float, u);
}
__device__ __forceinline__ void a16(void* lds, const void* g) {
    __builtin_amdgcn_global_load_lds(
        (const __attribute__((address_space(1))) unsigned int*)g,
        (__attribute__((address_space(3))) unsigned int*)lds, 16, 0, 0);
}
__device__ __forceinline__ float gelu_exact(float v) {
    return 0.5f * v * (1.0f + erff(v * 0.70710678118654752f));
}

// ---------------------------------------------------------------------------
// LayerNorm -> split bf16 hi/lo. One wave per 512-f32 row, block = 4 rows.
// ---------------------------------------------------------------------------
__global__ __launch_bounds__(256) void ln_k(const float* __restrict__ x,
                                            const float* __restrict__ g,
                                            const float* __restrict__ bta,
                                            u16* __restrict__ oh,
                                            u16* __restrict__ ol) {
    const int lane = threadIdx.x & 63;
    const int row  = (blockIdx.x << 2) + (threadIdx.x >> 6);
    const float* xr = x + ((size_t)row << 9) + (lane << 3);
    float v[8];
    *(float4*)&v[0] = *(const float4*)xr;
    *(float4*)&v[4] = *(const float4*)(xr + 4);
    float s = 0.f, ss = 0.f;
#pragma unroll
    for (int i = 0; i < 8; i++) { s += v[i]; ss += v[i] * v[i]; }
#pragma unroll
    for (int m = 32; m; m >>= 1) {
        s  += __shfl_xor(s, m, 64);
        ss += __shfl_xor(ss, m, 64);
    }
    const float mu   = s * (1.0f / 512.0f);
    const float rstd = rsqrtf(ss * (1.0f / 512.0f) - mu * mu + 1e-5f);
    float gg[8], bb[8];
    *(float4*)&gg[0] = *(const float4*)(g + (lane << 3));
    *(float4*)&gg[4] = *(const float4*)(g + (lane << 3) + 4);
    *(float4*)&bb[0] = *(const float4*)(bta + (lane << 3));
    *(float4*)&bb[4] = *(const float4*)(bta + (lane << 3) + 4);
    union { u16 us[8]; uint4 q; } H, L;
#pragma unroll
    for (int i = 0; i < 8; i++) {
        float r = (v[i] - mu) * rstd * gg[i] + bb[i];
        u16 hi = f2bf(r);
        H.us[i] = hi;
        L.us[i] = f2bf(r - bf2f(hi));
    }
    const size_t o = ((size_t)row << 9) + (lane << 3);
    *(uint4*)&oh[o] = H.q;
    *(uint4*)&ol[o] = L.q;
}

// ---------------------------------------------------------------------------
// Weight transpose + RTNE bf16: src[K][N] f32 -> dh[N][K]. Grid (N/64,K/64).
// ---------------------------------------------------------------------------
__global__ __launch_bounds__(256) void wtconv_k(const float* __restrict__ src,
                                                u16* __restrict__ dh,
                                                int K, int N) {
    __shared__ float t[64][65];
    const int tid = threadIdx.x;
    const int n0 = blockIdx.x << 6, k0 = blockIdx.y << 6;
    {
        const int kr = tid >> 2, nc = (tid & 3) << 4;
        const float* p = src + (size_t)(k0 + kr) * N + n0 + nc;
#pragma unroll
        for (int i = 0; i < 4; i++)
            *(float4*)&t[kr][nc + (i << 2)] = *(const float4*)(p + (i << 2));
    }
    __syncthreads();
    {
        const int nr = tid >> 2, kc = (tid & 3) << 4;
        union { u16 us[16]; uint4 q[2]; } H;
#pragma unroll
        for (int i = 0; i < 16; i++) H.us[i] = f2bf(t[kc + i][nr]);
        const size_t o = (size_t)(n0 + nr) * K + k0 + kc;
        *(uint4*)&dh[o] = H.q[0]; *(uint4*)&dh[o + 8] = H.q[1];
    }
}

// ---------------------------------------------------------------------------
// 2-term split MFMA GEMM: C = A[M,K]B[K,N]; A split Ah/Al [M][K], B single
// Bh [N][K]. 128x128 tile, BK=32, 4 waves 2x2, 32 MFMA : 12 ds_read.
// EPI 0: qkv scatter (q f32 | kh single [bh][key][d] | vth/vtl [bh][d][key])
// EPI 1/3: +bias +res -> Cf f32     EPI 2: +bias, GELU -> Ch/Cl bf16 split
// ---------------------------------------------------------------------------
template <int EPI>
__global__ __launch_bounds__(256, 2) void sgemm_k(
    const u16* __restrict__ Ah, const u16* __restrict__ Al,
    const u16* __restrict__ Bh,
    const float* __restrict__ bias, const float* __restrict__ res,
    float* __restrict__ Cf, u16* __restrict__ Ch, u16* __restrict__ Cl,
    u16* __restrict__ Dh, u16* __restrict__ Dl,
    int M, int N, int K) {
    __shared__ u16 sm[12288];  // Ah[0) Al[4096) Bh[8192) tiles: r*32 + pos*8
    const int tid = threadIdx.x;
    const int lane = tid & 63, wv = tid >> 6;
    const int col = lane & 15, quad = lane >> 4;
    const int wm = (wv & 1) << 6, wn = (wv >> 1) << 6;
    const int bm = blockIdx.y << 7, bn = blockIdx.x << 7;

    const int r0 = tid >> 2,         c0 = (tid & 3) ^ ((r0 >> 1) & 3);
    const int r1 = (tid + 256) >> 2, c1 = (tid & 3) ^ ((r1 >> 1) & 3);
    const u16* Ag0  = Ah + (size_t)(bm + r0) * K + c0 * 8;
    const u16* Ag1  = Ah + (size_t)(bm + r1) * K + c1 * 8;
    const u16* ALg0 = Al + (size_t)(bm + r0) * K + c0 * 8;
    const u16* ALg1 = Al + (size_t)(bm + r1) * K + c1 * 8;
    const u16* Bg0  = Bh + (size_t)(bn + r0) * K + c0 * 8;
    const u16* Bg1  = Bh + (size_t)(bn + r1) * K + c1 * 8;
    u16* l0 = &sm[wv * 512];
    u16* l1 = &sm[wv * 512 + 2048];
    const int swz = (col >> 1) & 3;
    const f32x4 z4 = {0.f, 0.f, 0.f, 0.f};
    f32x4 acc[4][4] = {{z4,z4,z4,z4},{z4,z4,z4,z4},{z4,z4,z4,z4},{z4,z4,z4,z4}};

    for (int k0 = 0; k0 < K; k0 += 32) {
        __syncthreads();
        a16(l0,         Ag0 + k0);  a16(l1,         Ag1 + k0);
        a16(l0 + 4096,  ALg0 + k0); a16(l1 + 4096,  ALg1 + k0);
        a16(l0 + 8192,  Bg0 + k0);  a16(l1 + 8192,  Bg1 + k0);
        __syncthreads();
        bf16x8 af[4][2];
#pragma unroll
        for (int mt = 0; mt < 4; mt++) {
            const int ra = (wm + (mt << 4) + col) * 32 + ((quad ^ swz) << 3);
            af[mt][0] = *(const bf16x8*)&sm[ra];
            af[mt][1] = *(const bf16x8*)&sm[4096 + ra];
        }
#pragma unroll
        for (int nt = 0; nt < 4; nt++) {
            const int rb = (wn + (nt << 4) + col) * 32 + ((quad ^ swz) << 3);
            bf16x8 bh_ = *(const bf16x8*)&sm[8192 + rb];
#pragma unroll
            for (int mt = 0; mt < 4; mt++) {
                acc[mt][nt] = __builtin_amdgcn_mfma_f32_16x16x32_bf16(af[mt][0], bh_, acc[mt][nt], 0, 0, 0);
                acc[mt][nt] = __builtin_amdgcn_mfma_f32_16x16x32_bf16(af[mt][1], bh_, acc[mt][nt], 0, 0, 0);
            }
        }
    }

    float bs[4];
    if constexpr (EPI >= 1) {
#pragma unroll
        for (int nt = 0; nt < 4; nt++) bs[nt] = bias[bn + wn + (nt << 4) + col];
    }
#pragma unroll
    for (int mt = 0; mt < 4; mt++) {
#pragma unroll
        for (int rr = 0; rr < 4; rr++) {
            const int row = bm + wm + (mt << 4) + (quad << 2) + rr;
#pragma unroll
            for (int nt = 0; nt < 4; nt++) {
                const int colg = bn + wn + (nt << 4) + col;
                float v = acc[mt][nt][rr];
                if constexpr (EPI == 0) {
                    const int b = row >> 11, key = row & 2047;
                    if (bn < 512) {
                        Cf[((size_t)row << 9) + colg] = v;
                    } else if (bn < 1024) {
                        const int hd = (colg - 512) >> 6, d = colg & 63;
                        Ch[((size_t)((b << 3) + hd) << 17) + (key << 6) + d] = f2bf(v);
                    } else {
                        const int hd = (colg - 1024) >> 6, d = colg & 63;
                        const size_t base = ((size_t)((b << 3) + hd) << 17) + ((size_t)d << 11) + key;
                        u16 hi = f2bf(v);
                        Dh[base] = hi; Dl[base] = f2bf(v - bf2f(hi));
                    }
                } else if constexpr (EPI == 2) {
                    v = gelu_exact(v + bs[nt]);
                    const size_t o = (size_t)row * N + colg;
                    u16 hi = f2bf(v);
                    Ch[o] = hi; Cl[o] = f2bf(v - bf2f(hi));
                } else {
                    const size_t o = (size_t)row * N + colg;
                    Cf[o] = v + bs[nt] + res[o];
                }
            }
        }
    }
}

// ---------------------------------------------------------------------------
// Flash attention: 128-thr blocks (2 waves), 64 q-rows/block, 2 q-subtiles
// per wave. K single bf16, Q split, P single, V split. Grid (32 qt, 32 bh).
// LDS 32KB (u16 idx): Kh[0,4K) Vh[4K,8K) Vl[8K,12K) Ph[12K,16K).
// Row swizzle pos = c ^ (r&7). 2 barriers/jt. 64 MFMA per wave-jt.
// ---------------------------------------------------------------------------
__global__ __launch_bounds__(128, 2) void attn_k(const float* __restrict__ q,
                                                 const u16* __restrict__ kh,
                                                 const u16* __restrict__ vth,
                                                 const u16* __restrict__ vtl,
                                                 u16* __restrict__ ah,
                                                 u16* __restrict__ al) {
    __shared__ u16 sm[16384];
    const int tid = threadIdx.x;
    const int lane = tid & 63, wv = tid >> 6;   // wv in {0,1}
    const int col = lane & 15, quad = lane >> 4;
    const int qt = blockIdx.x, bh = blockIdx.y;
    const int b = bh >> 3, h = bh & 7;
    const size_t tok0 = (size_t)b * SEQ;
    const size_t bhK = (size_t)bh << 17;
    const int q0 = qt << 6;

    // Q fragments, both subtiles (B-operand; 0.125 scale folded in).
    bf16x8 qfh[2][2], qfl[2][2];
#pragma unroll
    for (int sub = 0; sub < 2; sub++) {
        const int qrow = q0 + (wv << 5) + (sub << 4) + col;
        const float* qp = q + ((tok0 + qrow) << 9) + (h << 6) + (quad << 3);
#pragma unroll
        for (int kc = 0; kc < 2; kc++) {
            float v[8];
            *(float4*)&v[0] = *(const float4*)(qp + (kc << 5));
            *(float4*)&v[4] = *(const float4*)(qp + (kc << 5) + 4);
            union { u16 us[8]; bf16x8 v8; } H, L;
#pragma unroll
            for (int i = 0; i < 8; i++) {
                float f = v[i] * 0.125f;
                u16 hi = f2bf(f);
                H.us[i] = hi;
                L.us[i] = f2bf(f - bf2f(hi));
            }
            qfh[sub][kc] = H.v8; qfl[sub][kc] = L.v8;
        }
    }

    const f32x4 z4 = {0.f, 0.f, 0.f, 0.f};
    f32x4 o[2][4] = {{z4, z4, z4, z4}, {z4, z4, z4, z4}};
    float m_run[2] = {-1e30f, -1e30f}, l_run[2] = {0.f, 0.f};

    // staging: 512 chunks/tile, wave wv issue j covers chunks (j*2+wv)*64+lane
    size_t kbz[4], vbz[4];
    int doff[4];
#pragma unroll
    for (int j = 0; j < 4; j++) {
        const int C = (((j << 1) + wv) << 6) + lane;
        const int sr = C >> 3, sp = (C & 7) ^ (sr & 7);
        kbz[j] = bhK + ((size_t)sr << 6) + (sp << 3);   // + jt*4096
        vbz[j] = bhK + ((size_t)sr << 11) + (sp << 3);  // + jt*64
        doff[j] = (((j << 1) + wv) << 9);               // u16 idx of chunk base
    }

    for (int jt = 0; jt < 32; jt++) {
        __syncthreads();  // prior jt's K/V reads complete
        {
            const size_t ko = (size_t)jt << 12, vo = (size_t)jt << 6;
#pragma unroll
            for (int j = 0; j < 4; j++) {
                a16(&sm[doff[j]],         kh  + kbz[j] + ko);
                a16(&sm[4096 + doff[j]],  vth + vbz[j] + vo);
                a16(&sm[8192 + doff[j]],  vtl + vbz[j] + vo);
            }
        }
        __syncthreads();

        // ---- St[key][q] = K · Qᵀ (K frag read once, feeds both subtiles) ----
        f32x4 st0[4] = {z4, z4, z4, z4}, st1[4] = {z4, z4, z4, z4};
#pragma unroll
        for (int kb = 0; kb < 4; kb++) {
            const int key = (kb << 4) + col;
            const int r64 = key << 6, k7 = key & 7;
#pragma unroll
            for (int kc = 0; kc < 2; kc++) {
                const int ofs = r64 + ((((kc << 2) + quad) ^ k7) << 3);
                bf16x8 khf = *(const bf16x8*)&sm[ofs];
                st0[kb] = __builtin_amdgcn_mfma_f32_16x16x32_bf16(khf, qfh[0][kc], st0[kb], 0, 0, 0);
                st0[kb] = __builtin_amdgcn_mfma_f32_16x16x32_bf16(khf, qfl[0][kc], st0[kb], 0, 0, 0);
                st1[kb] = __builtin_amdgcn_mfma_f32_16x16x32_bf16(khf, qfh[1][kc], st1[kb], 0, 0, 0);
                st1[kb] = __builtin_amdgcn_mfma_f32_16x16x32_bf16(khf, qfl[1][kc], st1[kb], 0, 0, 0);
            }
        }

        // ---- online softmax + P->LDS per subtile ----
#pragma unroll
        for (int sub = 0; sub < 2; sub++) {
            f32x4* st = sub ? st1 : st0;
            float mx = st[0][0];
#pragma unroll
            for (int kb = 0; kb < 4; kb++)
#pragma unroll
                for (int r = 0; r < 4; r++) mx = fmaxf(mx, st[kb][r]);
            mx = fmaxf(mx, __shfl_xor(mx, 16));
            mx = fmaxf(mx, __shfl_xor(mx, 32));
            const float mn = fmaxf(m_run[sub], mx);
            const float alp = __expf(m_run[sub] - mn);
            m_run[sub] = mn;
            float p[16];
            float rs = 0.0f;
#pragma unroll
            for (int kb = 0; kb < 4; kb++)
#pragma unroll
                for (int r = 0; r < 4; r++) {
                    float e = __expf(st[kb][r] - mn);
                    p[(kb << 2) + r] = e;
                    rs += e;
                }
            rs += __shfl_xor(rs, 16);
            rs += __shfl_xor(rs, 32);
            l_run[sub] = l_run[sub] * alp + rs;
            float aO[4];
#pragma unroll
            for (int r = 0; r < 4; r++) aO[r] = __shfl(alp, (quad << 2) + r);
#pragma unroll
            for (int db = 0; db < 4; db++) {
                o[sub][db][0] *= aO[0]; o[sub][db][1] *= aO[1];
                o[sub][db][2] *= aO[2]; o[sub][db][3] *= aO[3];
            }
            // P (single, RTNE) -> LDS row-major P[q][key], swizzled
            const int prow = (wv << 5) + (sub << 4) + col;
            const int p64 = prow << 6, p7 = prow & 7;
#pragma unroll
            for (int kb = 0; kb < 4; kb++) {
                u16x4 hv;
#pragma unroll
                for (int r = 0; r < 4; r++) hv[r] = f2bf(p[(kb << 2) + r]);
                const int c = (kb << 1) + (quad >> 1);
                *(u16x4*)&sm[12288 + p64 + ((c ^ p7) << 3) + ((quad & 1) << 2)] = hv;
            }
        }

        // ---- P fragments (wave-private rows; same-wave RAW via lgkmcnt) ----
        bf16x8 pf[2][2];
#pragma unroll
        for (int sub = 0; sub < 2; sub++) {
            const int prow = (wv << 5) + (sub << 4) + col;
            const int p64 = prow << 6, p7 = prow & 7;
#pragma unroll
            for (int kc = 0; kc < 2; kc++)
                pf[sub][kc] = *(const bf16x8*)&sm[12288 + p64 + ((((kc << 2) + quad) ^ p7) << 3)];
        }

        // ---- O += P · V (V frags read once, feed both subtiles) ----
#pragma unroll
        for (int db = 0; db < 4; db++) {
            const int d = (db << 4) + col;
            const int v64 = 4096 + (d << 6), d7 = d & 7;
#pragma unroll
            for (int kc = 0; kc < 2; kc++) {
                const int ofs = v64 + ((((kc << 2) + quad) ^ d7) << 3);
                bf16x8 vh = *(const bf16x8*)&sm[ofs];
                bf16x8 vl = *(const bf16x8*)&sm[4096 + ofs];
                o[0][db] = __builtin_amdgcn_mfma_f32_16x16x32_bf16(pf[0][kc], vh, o[0][db], 0, 0, 0);
                o[0][db] = __builtin_amdgcn_mfma_f32_16x16x32_bf16(pf[0][kc], vl, o[0][db], 0, 0, 0);
                o[1][db] = __builtin_amdgcn_mfma_f32_16x16x32_bf16(pf[1][kc], vh, o[1][db], 0, 0, 0);
                o[1][db] = __builtin_amdgcn_mfma_f32_16x16x32_bf16(pf[1][kc], vl, o[1][db], 0, 0, 0);
            }
        }
    }

    // ---- epilogue: O/l -> split bf16 attended [tok][h*64+d] ----
#pragma unroll
    for (int sub = 0; sub < 2; sub++) {
        float linv[4];
#pragma unroll
        for (int r = 0; r < 4; r++) linv[r] = 1.0f / __shfl(l_run[sub], (quad << 2) + r);
#pragma unroll
        for (int r = 0; r < 4; r++) {
            const size_t rowo = ((tok0 + q0 + (wv << 5) + (sub << 4) + (quad << 2) + r) << 9)
                                + (h << 6) + col;
#pragma unroll
            for (int db = 0; db < 4; db++) {
                float v = o[sub][db][r] * linv[r];
                u16 hi = f2bf(v);
                ah[rowo + (db << 4)] = hi;
                al[rowo + (db << 4)] = f2bf(v - bf2f(hi));
            }
        }
    }
}

// ---------------------------------------------------------------------------
extern "C" void kernel_launch(void* const* d_in, const int* in_sizes, int n_in,
                              void* d_out, int out_size, void* d_ws, size_t ws_size,
                              hipStream_t stream) {
    const float* x     = (const float*)d_in[0];
    const float* ln1_g = (const float*)d_in[1];
    const float* ln1_b = (const float*)d_in[2];
    const float* w_qkv = (const float*)d_in[3];
    const float* w_out = (const float*)d_in[4];
    const float* b_out = (const float*)d_in[5];
    const float* ln2_g = (const float*)d_in[6];
    const float* ln2_b = (const float*)d_in[7];
    const float* w1    = (const float*)d_in[8];
    const float* b1    = (const float*)d_in[9];
    const float* w2    = (const float*)d_in[10];
    const float* b2    = (const float*)d_in[11];
    float* out = (float*)d_out;

    u16* wqkvh = (u16*)d_ws;                       // [1536][512]
    u16* wouth = wqkvh + 1536 * 512;               // [512][512]
    u16* w1h   = wouth + 512 * 512;                // [1024][512]
    u16* w2h   = w1h + 1024 * 512;                 // [512][1024]
    u16* R1    = w2h + 512 * 1024;
    u16* hh = R1, *hl = R1 + (size_t)TOKENS * 512;
    float* R2  = (float*)(R1 + (size_t)2 * TOKENS * 512);  // q -> x2
    float* qbuf = R2, *x2 = R2;
    u16* R3  = (u16*)(R2 + (size_t)TOKENS * 512);
    u16* kh  = R3;                                 // [32][2048][64]
    u16* vth = kh + (size_t)32 * 131072;           // [32][64][2048]
    u16* vtl = vth + (size_t)32 * 131072;
    u16* gh  = R3, *gl = R3 + (size_t)TOKENS * 1024;  // gelu out (aliases k/v)

    wtconv_k<<<dim3(24, 8), 256, 0, stream>>>(w_qkv, wqkvh, 512, 1536);
    wtconv_k<<<dim3(8, 8),  256, 0, stream>>>(w_out, wouth, 512, 512);
    wtconv_k<<<dim3(16, 8), 256, 0, stream>>>(w1, w1h, 512, 1024);
    wtconv_k<<<dim3(8, 16), 256, 0, stream>>>(w2, w2h, 1024, 512);

    ln_k<<<TOKENS / 4, 256, 0, stream>>>(x, ln1_g, ln1_b, hh, hl);
    sgemm_k<0><<<dim3(12, 64), 256, 0, stream>>>(hh, hl, wqkvh, nullptr, nullptr,
                                                 qbuf, kh, nullptr, vth, vtl,
                                                 TOKENS, 1536, 512);
    attn_k<<<dim3(32, 32), 128, 0, stream>>>(qbuf, kh, vth, vtl, hh, hl);
    sgemm_k<1><<<dim3(4, 64), 256, 0, stream>>>(hh, hl, wouth, b_out, x,
                                                x2, nullptr, nullptr, nullptr, nullptr,
                                                TOKENS, 512, 512);
    ln_k<<<TOKENS / 4, 256, 0, stream>>>(x2, ln2_g, ln2_b, hh, hl);
    sgemm_k<2><<<dim3(8, 64), 256, 0, stream>>>(hh, hl, w1h, b1, nullptr,
                                                nullptr, gh, gl, nullptr, nullptr,
                                                TOKENS, 1024, 512);
    sgemm_k<3><<<dim3(4, 64), 256, 0, stream>>>(gh, gl, w2h, b2, x2,
                                                out, nullptr, nullptr, nullptr, nullptr,
                                                TOKENS, 512, 1024);
}

// Round 6
// 336.109 us; speedup vs baseline: 5.4211x; 1.0704x over previous
//
#include <hip/hip_runtime.h>
#include <math.h>

// TransformerBlock for MI355X — round 6: software-pipelined staging.
// Numerics identical to round 5 (activations split bf16, weights/K/P single).
// attn: K double-buffered + V latency-hidden, raw asm barriers w/ vmcnt(4).
// sgemm: A/B ping-pong double-buffer, one asm barrier per k-step.
// ws layout (~71 MB): wT bf16 | R1 h/att/h2 hi,lo | R2 q->x2 f32 | R3 kh,vth,vtl -> gh,gl

#define TOKENS 8192
#define SEQ    2048
typedef unsigned short u16;
typedef __attribute__((ext_vector_type(8))) short bf16x8;
typedef __attribute__((ext_vector_type(4))) float f32x4;
typedef __attribute__((ext_vector_type(4))) unsigned short u16x4;

// raw barrier: wait selected vm loads + own LDS queue, then s_barrier.
// Bypasses the compiler's vmcnt(0)-drain-before-__syncthreads.
#define BAR_V0 asm volatile("s_waitcnt vmcnt(0) lgkmcnt(0)\n\ts_barrier" ::: "memory")
#define BAR_V4 asm volatile("s_waitcnt vmcnt(4) lgkmcnt(0)\n\ts_barrier" ::: "memory")

__device__ __forceinline__ u16 f2bf(float f) {
    unsigned u = __builtin_bit_cast(unsigned, f);
    u += 0x7fffu + ((u >> 16) & 1u);
    return (u16)(u >> 16);
}
__device__ __forceinline__ float bf2f(u16 h) {
    unsigned u = ((unsigned)h) << 16;
    return __builtin_bit_cast(float, u);
}
__device__ __forceinline__ void a16(void* lds, const void* g) {
    __builtin_amdgcn_global_load_lds(
        (const __attribute__((address_space(1))) unsigned int*)g,
        (__attribute__((address_space(3))) unsigned int*)lds, 16, 0, 0);
}
__device__ __forceinline__ float gelu_exact(float v) {
    return 0.5f * v * (1.0f + erff(v * 0.70710678118654752f));
}

// ---------------------------------------------------------------------------
// LayerNorm -> split bf16 hi/lo. One wave per 512-f32 row, block = 4 rows.
// ---------------------------------------------------------------------------
__global__ __launch_bounds__(256) void ln_k(const float* __restrict__ x,
                                            const float* __restrict__ g,
                                            const float* __restrict__ bta,
                                            u16* __restrict__ oh,
                                            u16* __restrict__ ol) {
    const int lane = threadIdx.x & 63;
    const int row  = (blockIdx.x << 2) + (threadIdx.x >> 6);
    const float* xr = x + ((size_t)row << 9) + (lane << 3);
    float v[8];
    *(float4*)&v[0] = *(const float4*)xr;
    *(float4*)&v[4] = *(const float4*)(xr + 4);
    float s = 0.f, ss = 0.f;
#pragma unroll
    for (int i = 0; i < 8; i++) { s += v[i]; ss += v[i] * v[i]; }
#pragma unroll
    for (int m = 32; m; m >>= 1) {
        s  += __shfl_xor(s, m, 64);
        ss += __shfl_xor(ss, m, 64);
    }
    const float mu   = s * (1.0f / 512.0f);
    const float rstd = rsqrtf(ss * (1.0f / 512.0f) - mu * mu + 1e-5f);
    float gg[8], bb[8];
    *(float4*)&gg[0] = *(const float4*)(g + (lane << 3));
    *(float4*)&gg[4] = *(const float4*)(g + (lane << 3) + 4);
    *(float4*)&bb[0] = *(const float4*)(bta + (lane << 3));
    *(float4*)&bb[4] = *(const float4*)(bta + (lane << 3) + 4);
    union { u16 us[8]; uint4 q; } H, L;
#pragma unroll
    for (int i = 0; i < 8; i++) {
        float r = (v[i] - mu) * rstd * gg[i] + bb[i];
        u16 hi = f2bf(r);
        H.us[i] = hi;
        L.us[i] = f2bf(r - bf2f(hi));
    }
    const size_t o = ((size_t)row << 9) + (lane << 3);
    *(uint4*)&oh[o] = H.q;
    *(uint4*)&ol[o] = L.q;
}

// ---------------------------------------------------------------------------
// All four weight transposes in one launch (512 blocks of 64x64 tiles).
// src[K][N] f32 -> dst[N][K] bf16 (RTNE).
// ---------------------------------------------------------------------------
__global__ __launch_bounds__(256) void wtall_k(const float* __restrict__ wqkv,
                                               const float* __restrict__ wout,
                                               const float* __restrict__ w1,
                                               const float* __restrict__ w2,
                                               u16* __restrict__ dqkv,
                                               u16* __restrict__ dout,
                                               u16* __restrict__ d1,
                                               u16* __restrict__ d2) {
    __shared__ float t[64][65];
    int b = blockIdx.x;
    const float* src; u16* dst; int K, N, n0, k0;
    if (b < 192)      { src = wqkv; dst = dqkv; K = 512;  N = 1536; n0 = (b % 24) << 6; k0 = (b / 24) << 6; }
    else if (b < 256) { b -= 192; src = wout; dst = dout; K = 512;  N = 512;  n0 = (b & 7) << 6;  k0 = (b >> 3) << 6; }
    else if (b < 384) { b -= 256; src = w1;   dst = d1;   K = 512;  N = 1024; n0 = (b & 15) << 6; k0 = (b >> 4) << 6; }
    else              { b -= 384; src = w2;   dst = d2;   K = 1024; N = 512;  n0 = (b & 7) << 6;  k0 = (b >> 3) << 6; }
    const int tid = threadIdx.x;
    {
        const int kr = tid >> 2, nc = (tid & 3) << 4;
        const float* p = src + (size_t)(k0 + kr) * N + n0 + nc;
#pragma unroll
        for (int i = 0; i < 4; i++)
            *(float4*)&t[kr][nc + (i << 2)] = *(const float4*)(p + (i << 2));
    }
    __syncthreads();
    {
        const int nr = tid >> 2, kc = (tid & 3) << 4;
        union { u16 us[16]; uint4 q[2]; } H;
#pragma unroll
        for (int i = 0; i < 16; i++) H.us[i] = f2bf(t[kc + i][nr]);
        const size_t o = (size_t)(n0 + nr) * K + k0 + kc;
        *(uint4*)&dst[o] = H.q[0];
        *(uint4*)&dst[o + 8] = H.q[1];
    }
}

// ---------------------------------------------------------------------------
// 2-term split MFMA GEMM, double-buffered staging, asm barriers.
// C = A[M,K]B[K,N]; A split Ah/Al [M][K], B single Bh [N][K].
// 128x128 tile, BK=32, 4 waves 2x2, 32 MFMA : 12 ds_read per k-step.
// EPI 0: qkv scatter (q f32 | kh [bh][key][d] | vth/vtl [bh][d][key])
// EPI 1/3: +bias +res -> Cf f32     EPI 2: +bias, GELU -> Ch/Cl bf16 split
// ---------------------------------------------------------------------------
template <int EPI>
__global__ __launch_bounds__(256, 2) void sgemm_k(
    const u16* __restrict__ Ah, const u16* __restrict__ Al,
    const u16* __restrict__ Bh,
    const float* __restrict__ bias, const float* __restrict__ res,
    float* __restrict__ Cf, u16* __restrict__ Ch, u16* __restrict__ Cl,
    u16* __restrict__ Dh, u16* __restrict__ Dl,
    int M, int N, int K) {
    __shared__ u16 sm[24576];  // two 12288-u16 buffers: Ah|Al|Bh
    const int tid = threadIdx.x;
    const int lane = tid & 63, wv = tid >> 6;
    const int col = lane & 15, quad = lane >> 4;
    const int wm = (wv & 1) << 6, wn = (wv >> 1) << 6;
    const int bm = blockIdx.y << 7, bn = blockIdx.x << 7;

    const int r0 = tid >> 2,         c0 = (tid & 3) ^ ((r0 >> 1) & 3);
    const int r1 = (tid + 256) >> 2, c1 = (tid & 3) ^ ((r1 >> 1) & 3);
    const u16* Ag0  = Ah + (size_t)(bm + r0) * K + c0 * 8;
    const u16* Ag1  = Ah + (size_t)(bm + r1) * K + c1 * 8;
    const u16* ALg0 = Al + (size_t)(bm + r0) * K + c0 * 8;
    const u16* ALg1 = Al + (size_t)(bm + r1) * K + c1 * 8;
    const u16* Bg0  = Bh + (size_t)(bn + r0) * K + c0 * 8;
    const u16* Bg1  = Bh + (size_t)(bn + r1) * K + c1 * 8;
    const int lw0 = wv * 512, lw1 = wv * 512 + 2048;
    const int swz = (col >> 1) & 3;
    const f32x4 z4 = {0.f, 0.f, 0.f, 0.f};
    f32x4 acc[4][4] = {{z4,z4,z4,z4},{z4,z4,z4,z4},{z4,z4,z4,z4},{z4,z4,z4,z4}};

    // prologue: stage k-step 0 into buffer 0
    a16(&sm[lw0],        Ag0);  a16(&sm[lw1],        Ag1);
    a16(&sm[lw0 + 4096], ALg0); a16(&sm[lw1 + 4096], ALg1);
    a16(&sm[lw0 + 8192], Bg0);  a16(&sm[lw1 + 8192], Bg1);

    int ib = 0;
    for (int k0 = 0; k0 < K; k0 += 32, ib ^= 1) {
        BAR_V0;  // buffer ib ready; all waves past reads of buffer ib^1
        if (k0 + 32 < K) {
            const int nb = (ib ^ 1) * 12288;
            const int kn = k0 + 32;
            a16(&sm[nb + lw0],        Ag0 + kn);  a16(&sm[nb + lw1],        Ag1 + kn);
            a16(&sm[nb + lw0 + 4096], ALg0 + kn); a16(&sm[nb + lw1 + 4096], ALg1 + kn);
            a16(&sm[nb + lw0 + 8192], Bg0 + kn);  a16(&sm[nb + lw1 + 8192], Bg1 + kn);
        }
        const int cb = ib * 12288;
        bf16x8 af[4][2];
#pragma unroll
        for (int mt = 0; mt < 4; mt++) {
            const int ra = cb + (wm + (mt << 4) + col) * 32 + ((quad ^ swz) << 3);
            af[mt][0] = *(const bf16x8*)&sm[ra];
            af[mt][1] = *(const bf16x8*)&sm[4096 + ra];
        }
#pragma unroll
        for (int nt = 0; nt < 4; nt++) {
            const int rb = cb + 8192 + (wn + (nt << 4) + col) * 32 + ((quad ^ swz) << 3);
            bf16x8 bh_ = *(const bf16x8*)&sm[rb];
#pragma unroll
            for (int mt = 0; mt < 4; mt++) {
                acc[mt][nt] = __builtin_amdgcn_mfma_f32_16x16x32_bf16(af[mt][0], bh_, acc[mt][nt], 0, 0, 0);
                acc[mt][nt] = __builtin_amdgcn_mfma_f32_16x16x32_bf16(af[mt][1], bh_, acc[mt][nt], 0, 0, 0);
            }
        }
    }

    float bs[4];
    if constexpr (EPI >= 1) {
#pragma unroll
        for (int nt = 0; nt < 4; nt++) bs[nt] = bias[bn + wn + (nt << 4) + col];
    }
#pragma unroll
    for (int mt = 0; mt < 4; mt++) {
#pragma unroll
        for (int rr = 0; rr < 4; rr++) {
            const int row = bm + wm + (mt << 4) + (quad << 2) + rr;
#pragma unroll
            for (int nt = 0; nt < 4; nt++) {
                const int colg = bn + wn + (nt << 4) + col;
                float v = acc[mt][nt][rr];
                if constexpr (EPI == 0) {
                    const int b = row >> 11, key = row & 2047;
                    if (bn < 512) {
                        Cf[((size_t)row << 9) + colg] = v;
                    } else if (bn < 1024) {
                        const int hd = (colg - 512) >> 6, d = colg & 63;
                        Ch[((size_t)((b << 3) + hd) << 17) + (key << 6) + d] = f2bf(v);
                    } else {
                        const int hd = (colg - 1024) >> 6, d = colg & 63;
                        const size_t base = ((size_t)((b << 3) + hd) << 17) + ((size_t)d << 11) + key;
                        u16 hi = f2bf(v);
                        Dh[base] = hi; Dl[base] = f2bf(v - bf2f(hi));
                    }
                } else if constexpr (EPI == 2) {
                    v = gelu_exact(v + bs[nt]);
                    const size_t o = (size_t)row * N + colg;
                    u16 hi = f2bf(v);
                    Ch[o] = hi; Cl[o] = f2bf(v - bf2f(hi));
                } else {
                    const size_t o = (size_t)row * N + colg;
                    Cf[o] = v + bs[nt] + res[o];
                }
            }
        }
    }
}

// ---------------------------------------------------------------------------
// Flash attention: 128-thr blocks (2 waves x 2 q-subtiles), grid (32,32).
// K double-buffered (prefetch jt+1); V staged at jt-top, first used after
// QK^T+softmax; raw asm barriers (vmcnt(4) keeps K prefetch in flight).
// LDS 40KB (u16 idx): Kh0[0,4K) Kh1[4K,8K) Vh[8K,12K) Vl[12K,16K) Ph[16K,20K)
// ---------------------------------------------------------------------------
__global__ __launch_bounds__(128, 2) void attn_k(const float* __restrict__ q,
                                                 const u16* __restrict__ kh,
                                                 const u16* __restrict__ vth,
                                                 const u16* __restrict__ vtl,
                                                 u16* __restrict__ ah,
                                                 u16* __restrict__ al) {
    __shared__ u16 sm[20480];
    const int tid = threadIdx.x;
    const int lane = tid & 63, wv = tid >> 6;   // wv in {0,1}
    const int col = lane & 15, quad = lane >> 4;
    const int qt = blockIdx.x, bh = blockIdx.y;
    const int b = bh >> 3, h = bh & 7;
    const size_t tok0 = (size_t)b * SEQ;
    const size_t bhK = (size_t)bh << 17;
    const int q0 = qt << 6;

    bf16x8 qfh[2][2], qfl[2][2];
#pragma unroll
    for (int sub = 0; sub < 2; sub++) {
        const int qrow = q0 + (wv << 5) + (sub << 4) + col;
        const float* qp = q + ((tok0 + qrow) << 9) + (h << 6) + (quad << 3);
#pragma unroll
        for (int kc = 0; kc < 2; kc++) {
            float v[8];
            *(float4*)&v[0] = *(const float4*)(qp + (kc << 5));
            *(float4*)&v[4] = *(const float4*)(qp + (kc << 5) + 4);
            union { u16 us[8]; bf16x8 v8; } H, L;
#pragma unroll
            for (int i = 0; i < 8; i++) {
                float f = v[i] * 0.125f;
                u16 hi = f2bf(f);
                H.us[i] = hi;
                L.us[i] = f2bf(f - bf2f(hi));
            }
            qfh[sub][kc] = H.v8; qfl[sub][kc] = L.v8;
        }
    }

    const f32x4 z4 = {0.f, 0.f, 0.f, 0.f};
    f32x4 o[2][4] = {{z4, z4, z4, z4}, {z4, z4, z4, z4}};
    float m_run[2] = {-1e30f, -1e30f}, l_run[2] = {0.f, 0.f};

    size_t kbz[4], vbz[4];
    int doff[4];
#pragma unroll
    for (int j = 0; j < 4; j++) {
        const int C = (((j << 1) + wv) << 6) + lane;
        const int sr = C >> 3, sp = (C & 7) ^ (sr & 7);
        kbz[j] = bhK + ((size_t)sr << 6) + (sp << 3);   // + jt*4096
        vbz[j] = bhK + ((size_t)sr << 11) + (sp << 3);  // + jt*64
        doff[j] = (((j << 1) + wv) << 9);
    }

    // prologue: stage K[0] into Kh0
#pragma unroll
    for (int j = 0; j < 4; j++) a16(&sm[doff[j]], kh + kbz[j]);

    int ib = 0;
    for (int jt = 0; jt < 32; jt++, ib ^= 1) {
        BAR_V0;  // K[jt] retired; all waves done with V[jt-1]/P[jt-1]
        {
            const size_t vo = (size_t)jt << 6;
#pragma unroll
            for (int j = 0; j < 4; j++) {
                a16(&sm[8192 + doff[j]],  vth + vbz[j] + vo);
                a16(&sm[12288 + doff[j]], vtl + vbz[j] + vo);
            }
            const size_t kon = (size_t)((jt + 1) & 31) << 12;
            const int nb = (ib ^ 1) << 12;
#pragma unroll
            for (int j = 0; j < 4; j++) a16(&sm[nb + doff[j]], kh + kbz[j] + kon);
        }

        const int cb = ib << 12;
        f32x4 st0[4] = {z4, z4, z4, z4}, st1[4] = {z4, z4, z4, z4};
#pragma unroll
        for (int kb = 0; kb < 4; kb++) {
            const int key = (kb << 4) + col;
            const int r64 = key << 6, k7 = key & 7;
#pragma unroll
            for (int kc = 0; kc < 2; kc++) {
                const int ofs = cb + r64 + ((((kc << 2) + quad) ^ k7) << 3);
                bf16x8 khf = *(const bf16x8*)&sm[ofs];
                st0[kb] = __builtin_amdgcn_mfma_f32_16x16x32_bf16(khf, qfh[0][kc], st0[kb], 0, 0, 0);
                st0[kb] = __builtin_amdgcn_mfma_f32_16x16x32_bf16(khf, qfl[0][kc], st0[kb], 0, 0, 0);
                st1[kb] = __builtin_amdgcn_mfma_f32_16x16x32_bf16(khf, qfh[1][kc], st1[kb], 0, 0, 0);
                st1[kb] = __builtin_amdgcn_mfma_f32_16x16x32_bf16(khf, qfl[1][kc], st1[kb], 0, 0, 0);
            }
        }

#pragma unroll
        for (int sub = 0; sub < 2; sub++) {
            f32x4* st = sub ? st1 : st0;
            float mx = st[0][0];
#pragma unroll
            for (int kb = 0; kb < 4; kb++)
#pragma unroll
                for (int r = 0; r < 4; r++) mx = fmaxf(mx, st[kb][r]);
            mx = fmaxf(mx, __shfl_xor(mx, 16));
            mx = fmaxf(mx, __shfl_xor(mx, 32));
            const float mn = fmaxf(m_run[sub], mx);
            const float alp = __expf(m_run[sub] - mn);
            m_run[sub] = mn;
            float p[16];
            float rs = 0.0f;
#pragma unroll
            for (int kb = 0; kb < 4; kb++)
#pragma unroll
                for (int r = 0; r < 4; r++) {
                    float e = __expf(st[kb][r] - mn);
                    p[(kb << 2) + r] = e;
                    rs += e;
                }
            rs += __shfl_xor(rs, 16);
            rs += __shfl_xor(rs, 32);
            l_run[sub] = l_run[sub] * alp + rs;
            float aO[4];
#pragma unroll
            for (int r = 0; r < 4; r++) aO[r] = __shfl(alp, (quad << 2) + r);
#pragma unroll
            for (int db = 0; db < 4; db++) {
                o[sub][db][0] *= aO[0]; o[sub][db][1] *= aO[1];
                o[sub][db][2] *= aO[2]; o[sub][db][3] *= aO[3];
            }
            const int prow = (wv << 5) + (sub << 4) + col;
            const int p64 = prow << 6, p7 = prow & 7;
#pragma unroll
            for (int kb = 0; kb < 4; kb++) {
                u16x4 hv;
#pragma unroll
                for (int r = 0; r < 4; r++) hv[r] = f2bf(p[(kb << 2) + r]);
                const int c = (kb << 1) + (quad >> 1);
                *(u16x4*)&sm[16384 + p64 + ((c ^ p7) << 3) + ((quad & 1) << 2)] = hv;
            }
        }

        BAR_V4;  // 8 V loads retired (in-order); 4 K prefetch stay in flight

        bf16x8 pf[2][2];
#pragma unroll
        for (int sub = 0; sub < 2; sub++) {
            const int prow = (wv << 5) + (sub << 4) + col;
            const int p64 = prow << 6, p7 = prow & 7;
#pragma unroll
            for (int kc = 0; kc < 2; kc++)
                pf[sub][kc] = *(const bf16x8*)&sm[16384 + p64 + ((((kc << 2) + quad) ^ p7) << 3)];
        }
#pragma unroll
        for (int db = 0; db < 4; db++) {
            const int d = (db << 4) + col;
            const int v64 = 8192 + (d << 6), d7 = d & 7;
#pragma unroll
            for (int kc = 0; kc < 2; kc++) {
                const int ofs = v64 + ((((kc << 2) + quad) ^ d7) << 3);
                bf16x8 vh = *(const bf16x8*)&sm[ofs];
                bf16x8 vl = *(const bf16x8*)&sm[4096 + ofs];
                o[0][db] = __builtin_amdgcn_mfma_f32_16x16x32_bf16(pf[0][kc], vh, o[0][db], 0, 0, 0);
                o[0][db] = __builtin_amdgcn_mfma_f32_16x16x32_bf16(pf[0][kc], vl, o[0][db], 0, 0, 0);
                o[1][db] = __builtin_amdgcn_mfma_f32_16x16x32_bf16(pf[1][kc], vh, o[1][db], 0, 0, 0);
                o[1][db] = __builtin_amdgcn_mfma_f32_16x16x32_bf16(pf[1][kc], vl, o[1][db], 0, 0, 0);
            }
        }
    }

#pragma unroll
    for (int sub = 0; sub < 2; sub++) {
        float linv[4];
#pragma unroll
        for (int r = 0; r < 4; r++) linv[r] = 1.0f / __shfl(l_run[sub], (quad << 2) + r);
#pragma unroll
        for (int r = 0; r < 4; r++) {
            const size_t rowo = ((tok0 + q0 + (wv << 5) + (sub << 4) + (quad << 2) + r) << 9)
                                + (h << 6) + col;
#pragma unroll
            for (int db = 0; db < 4; db++) {
                float v = o[sub][db][r] * linv[r];
                u16 hi = f2bf(v);
                ah[rowo + (db << 4)] = hi;
                al[rowo + (db << 4)] = f2bf(v - bf2f(hi));
            }
        }
    }
}

// ---------------------------------------------------------------------------
extern "C" void kernel_launch(void* const* d_in, const int* in_sizes, int n_in,
                              void* d_out, int out_size, void* d_ws, size_t ws_size,
                              hipStream_t stream) {
    const float* x     = (const float*)d_in[0];
    const float* ln1_g = (const float*)d_in[1];
    const float* ln1_b = (const float*)d_in[2];
    const float* w_qkv = (const float*)d_in[3];
    const float* w_out = (const float*)d_in[4];
    const float* b_out = (const float*)d_in[5];
    const float* ln2_g = (const float*)d_in[6];
    const float* ln2_b = (const float*)d_in[7];
    const float* w1    = (const float*)d_in[8];
    const float* b1    = (const float*)d_in[9];
    const float* w2    = (const float*)d_in[10];
    const float* b2    = (const float*)d_in[11];
    float* out = (float*)d_out;

    u16* wqkvh = (u16*)d_ws;                       // [1536][512]
    u16* wouth = wqkvh + 1536 * 512;               // [512][512]
    u16* w1h   = wouth + 512 * 512;                // [1024][512]
    u16* w2h   = w1h + 1024 * 512;                 // [512][1024]
    u16* R1    = w2h + 512 * 1024;
    u16* hh = R1, *hl = R1 + (size_t)TOKENS * 512;
    float* R2  = (float*)(R1 + (size_t)2 * TOKENS * 512);  // q -> x2
    float* qbuf = R2, *x2 = R2;
    u16* R3  = (u16*)(R2 + (size_t)TOKENS * 512);
    u16* kh  = R3;                                 // [32][2048][64]
    u16* vth = kh + (size_t)32 * 131072;           // [32][64][2048]
    u16* vtl = vth + (size_t)32 * 131072;
    u16* gh  = R3, *gl = R3 + (size_t)TOKENS * 1024;  // gelu out (aliases k/v)

    wtall_k<<<512, 256, 0, stream>>>(w_qkv, w_out, w1, w2, wqkvh, wouth, w1h, w2h);
    ln_k<<<TOKENS / 4, 256, 0, stream>>>(x, ln1_g, ln1_b, hh, hl);
    sgemm_k<0><<<dim3(12, 64), 256, 0, stream>>>(hh, hl, wqkvh, nullptr, nullptr,
                                                 qbuf, kh, nullptr, vth, vtl,
                                                 TOKENS, 1536, 512);
    attn_k<<<dim3(32, 32), 128, 0, stream>>>(qbuf, kh, vth, vtl, hh, hl);
    sgemm_k<1><<<dim3(4, 64), 256, 0, stream>>>(hh, hl, wouth, b_out, x,
                                                x2, nullptr, nullptr, nullptr, nullptr,
                                                TOKENS, 512, 512);
    ln_k<<<TOKENS / 4, 256, 0, stream>>>(x2, ln2_g, ln2_b, hh, hl);
    sgemm_k<2><<<dim3(8, 64), 256, 0, stream>>>(hh, hl, w1h, b1, nullptr,
                                                nullptr, gh, gl, nullptr, nullptr,
                                                TOKENS, 1024, 512);
    sgemm_k<3><<<dim3(4, 64), 256, 0, stream>>>(gh, gl, w2h, b2, x2,
                                                out, nullptr, nullptr, nullptr, nullptr,
                                                TOKENS, 512, 1024);
}